// Round 11
// baseline (100.354 us; speedup 1.0000x reference)
//
#include <hip/hip_runtime.h>

typedef unsigned short u16;
typedef unsigned int u32;
typedef unsigned long long u64;
typedef __attribute__((ext_vector_type(8))) short bfrag;    // 8 bf16 = 4 VGPRs
typedef __attribute__((ext_vector_type(4))) float f32x4;
typedef __attribute__((ext_vector_type(16))) float f32x16;
typedef __attribute__((ext_vector_type(4))) u32 u32x4;

#define QSCALE 0.18033688f   // 0.125 * log2(e): scores land in log2 domain

__device__ __forceinline__ u16 f2bf(float f) {
    unsigned u = __float_as_uint(f);
    u += 0x7FFFu + ((u >> 16) & 1u);           // RNE
    return (u16)(u >> 16);
}

__device__ __forceinline__ u32 cvt_pk_bf16(float lo, float hi) {
    u32 r;
    asm("v_cvt_pk_bf16_f32 %0, %1, %2" : "=v"(r) : "v"(lo), "v"(hi));
    return r;
}

__device__ __forceinline__ void glds16(const void* g, void* l) {
    __builtin_amdgcn_global_load_lds((__attribute__((address_space(1))) void*)g,
                                     (__attribute__((address_space(3))) void*)l,
                                     16, 0, 0);
}

__device__ __forceinline__ f32x16 mfma32(bfrag a, bfrag b, f32x16 c) {
    return __builtin_amdgcn_mfma_f32_32x32x16_bf16(a, b, c, 0, 0, 0);
}

#define WAIT_VM4()  asm volatile("s_waitcnt vmcnt(4)" ::: "memory")
#define WAIT_VM3()  asm volatile("s_waitcnt vmcnt(3)" ::: "memory")
#define WAIT_VM0()  asm volatile("s_waitcnt vmcnt(0)" ::: "memory")
#define BAR()       __builtin_amdgcn_s_barrier()
#define SCHED_FENCE() __builtin_amdgcn_sched_barrier(0)
#define PRIO(n)     __builtin_amdgcn_s_setprio(n)

// ---------------- convert: fp32 -> bf16 for x, Wq, Wk, Wv, Wo ----------------
__global__ __launch_bounds__(256) void convert_all(
    const float* __restrict__ x, const float* __restrict__ wq,
    const float* __restrict__ wk, const float* __restrict__ wv,
    const float* __restrict__ wo,
    u16* __restrict__ xb, u16* __restrict__ wqb, u16* __restrict__ wkb,
    u16* __restrict__ wvb, u16* __restrict__ wob) {
    const int XV = (2 * 2048 * 768) / 4;
    const int WV = (768 * 768) / 4;
    int i = blockIdx.x * 256 + threadIdx.x;
    if (i >= XV + 4 * WV) return;
    const float4* src; u16* dst; int off;
    if (i < XV) { src = (const float4*)x; dst = xb; off = i; }
    else {
        int j = i - XV; int z = j / WV; off = j - z * WV;
        src = (const float4*)(z == 0 ? wq : z == 1 ? wk : z == 2 ? wv : wo);
        dst = (z == 0 ? wqb : z == 1 ? wkb : z == 2 ? wvb : wob);
    }
    float4 v = src[off];
    u64 pk = (u64)f2bf(v.x)
        | ((u64)f2bf(v.y) << 16)
        | ((u64)f2bf(v.z) << 32)
        | ((u64)f2bf(v.w) << 48);
    *(u64*)(dst + off * 4) = pk;
}

// ---------------- GEMM core 128x128 (R8 version) ----------------
__device__ __forceinline__ void gemm_core(
    const u16* __restrict__ A, const u16* __restrict__ Bw, int m0,
    u16* a_lds, u16* b_lds, f32x4 acc[4][4]) {
    const int t = threadIdx.x;
    const int w = t >> 6, lane = t & 63, ln = lane & 15, lh = lane >> 4;
    const int wr = w >> 1, wc = w & 1;

    const int row0 = t >> 2;
    const int u0 = (t & 3) ^ ((row0 >> 1) & 3);
    const int row1 = row0 + 64;
    const int u1 = (t & 3) ^ ((row1 >> 1) & 3);
    const u16* ga0 = A + (m0 + row0) * 768 + u0 * 8;
    const u16* ga1 = A + (m0 + row1) * 768 + u1 * 8;
    const u16* gb0 = Bw + row0 * 768 + u0 * 8;
    const u16* gb1 = Bw + row1 * 768 + u1 * 8;
    u16* la = a_lds + w * 512;
    u16* lb = b_lds + w * 512;

    auto STAGE = [&](int k0, int bi) {
        glds16(ga0 + k0, la + bi * 4096);
        glds16(ga1 + k0, la + bi * 4096 + 2048);
        glds16(gb0 + k0, lb + bi * 4096);
        glds16(gb1 + k0, lb + bi * 4096 + 2048);
    };

    STAGE(0, 0);
    int cur = 0;
    for (int k0 = 0; k0 < 768; k0 += 32) {
        if (k0 + 32 < 768) {
            STAGE(k0 + 32, cur ^ 1);
            WAIT_VM4();
        } else {
            WAIT_VM0();
        }
        BAR();
        SCHED_FENCE();
        const u16* ab = a_lds + cur * 4096;
        const u16* bb = b_lds + cur * 4096;
        bfrag aF[4], bF[4];
#pragma unroll
        for (int i = 0; i < 4; i++) {
            int ra = wr * 64 + i * 16 + ln;
            aF[i] = *(const bfrag*)(ab + ra * 32 + ((lh ^ ((ra >> 1) & 3)) * 8));
            int rb = wc * 64 + i * 16 + ln;
            bF[i] = *(const bfrag*)(bb + rb * 32 + ((lh ^ ((rb >> 1) & 3)) * 8));
        }
#pragma unroll
        for (int i = 0; i < 4; i++)
#pragma unroll
            for (int j = 0; j < 4; j++)
                acc[i][j] = __builtin_amdgcn_mfma_f32_16x16x32_bf16(
                    aF[i], bF[j], acc[i][j], 0, 0, 0);
        SCHED_FENCE();
        BAR();
        cur ^= 1;
    }
}

// ---------------- QKV projection (R8 128x128 version) ----------------
__global__ __launch_bounds__(256) void gemm_qkv(
    const u16* __restrict__ xb,
    const u16* __restrict__ wqb, const u16* __restrict__ wkb, const u16* __restrict__ wvb,
    const float* __restrict__ bq, const float* __restrict__ bk, const float* __restrict__ bv,
    u16* __restrict__ q_ws, u16* __restrict__ k_ws, u16* __restrict__ vt_ws) {
    __shared__ __align__(16) u16 smem[16384];         // a_lds 8192 | b_lds 8192
    u16* a_lds = smem;
    u16* b_lds = smem + 8192;
    const int m0 = blockIdx.x * 128;
    const int z = blockIdx.y / 6, nb = blockIdx.y % 6;
    const u16* Bw = (z == 0 ? wqb : z == 1 ? wkb : wvb) + nb * 128 * 768;
    const float* bias = (z == 0 ? bq : z == 1 ? bk : bv);

    f32x4 acc[4][4] = {};
    gemm_core(xb, Bw, m0, a_lds, b_lds, acc);

    const int t = threadIdx.x, w = t >> 6, lane = t & 63, ln = lane & 15, lh = lane >> 4;
    const int wr = w >> 1, wc = w & 1;
    if (z == 2) {
        // ---- LDS transpose: T[n=128][m=128] u16, 16B units swizzled by n ----
        __syncthreads();
        char* T = (char*)smem;
#pragma unroll
        for (int j = 0; j < 4; j++) {
            int nt = wc * 64 + j * 16 + ln;
            float bb = bias[nb * 128 + nt];
#pragma unroll
            for (int i = 0; i < 4; i++) {
                int m0t = wr * 64 + i * 16 + lh * 4;
                u64 pk = (u64)f2bf(acc[i][j][0] + bb)
                    | ((u64)f2bf(acc[i][j][1] + bb) << 16)
                    | ((u64)f2bf(acc[i][j][2] + bb) << 32)
                    | ((u64)f2bf(acc[i][j][3] + bb) << 48);
                int off = nt * 256 + ((m0t * 2) ^ ((nt & 15) << 4));
                *(u64*)(T + off) = pk;
            }
        }
        __syncthreads();
        const int b = m0 >> 11, s0 = m0 & 2047;
#pragma unroll
        for (int c = 0; c < 8; c++) {
            int g = c * 256 + t;
            int nt = g >> 4, mc = (g & 15) * 8;
            int off = nt * 256 + ((mc * 2) ^ ((nt & 15) << 4));
            u32x4 v = *(const u32x4*)(T + off);
            int nl = nb * 128 + nt;
            int h = nl >> 6, d = nl & 63;
            *(u32x4*)(vt_ws + ((size_t)((b * 12 + h) * 64 + d)) * 2048 + s0 + mc) = v;
        }
    } else {
        u16* dst = (z == 0 ? q_ws : k_ws);
        const float sc = (z == 0) ? QSCALE : 1.0f;
#pragma unroll
        for (int j = 0; j < 4; j++) {
            int nl = nb * 128 + wc * 64 + j * 16 + ln;
            int h = nl >> 6, d = nl & 63;
            float bb = bias[nl];
#pragma unroll
            for (int i = 0; i < 4; i++)
#pragma unroll
                for (int r = 0; r < 4; r++) {
                    int m = m0 + wr * 64 + i * 16 + lh * 4 + r;
                    int b = m >> 11, s = m & 2047;
                    dst[((size_t)((b * 12 + h) * 2048 + s)) * 64 + d] = f2bf((acc[i][j][r] + bb) * sc);
                }
        }
    }
}

// ---------------- GEMM core 64x128 (for output projection) ----------------
__device__ __forceinline__ void gemm_core64(
    const u16* __restrict__ A, const u16* __restrict__ Bw, int m0,
    u16* a_lds, u16* b_lds, f32x4 acc[2][4]) {
    const int t = threadIdx.x;
    const int w = t >> 6, lane = t & 63, ln = lane & 15, lh = lane >> 4;
    const int wr = w >> 1, wc = w & 1;

    const int rowA = t >> 2;
    const int uA = (t & 3) ^ ((rowA >> 1) & 3);
    const int rowB1 = rowA + 64;
    const int uB1 = (t & 3) ^ ((rowB1 >> 1) & 3);
    const u16* ga  = A + (m0 + rowA) * 768 + uA * 8;
    const u16* gb0 = Bw + rowA * 768 + uA * 8;
    const u16* gb1 = Bw + rowB1 * 768 + uB1 * 8;
    u16* la = a_lds + w * 512;
    u16* lb = b_lds + w * 512;

    auto STAGE = [&](int k0, int bi) {
        glds16(ga + k0, la + bi * 2048);
        glds16(gb0 + k0, lb + bi * 4096);
        glds16(gb1 + k0, lb + bi * 4096 + 2048);
    };

    STAGE(0, 0);
    int cur = 0;
    for (int k0 = 0; k0 < 768; k0 += 32) {
        if (k0 + 32 < 768) {
            STAGE(k0 + 32, cur ^ 1);
            WAIT_VM3();
        } else {
            WAIT_VM0();
        }
        BAR();
        SCHED_FENCE();
        const u16* ab = a_lds + cur * 2048;
        const u16* bb = b_lds + cur * 4096;
        bfrag aF[2], bF[4];
#pragma unroll
        for (int i = 0; i < 2; i++) {
            int ra = wr * 32 + i * 16 + ln;
            aF[i] = *(const bfrag*)(ab + ra * 32 + ((lh ^ ((ra >> 1) & 3)) * 8));
        }
#pragma unroll
        for (int j = 0; j < 4; j++) {
            int rb = wc * 64 + j * 16 + ln;
            bF[j] = *(const bfrag*)(bb + rb * 32 + ((lh ^ ((rb >> 1) & 3)) * 8));
        }
#pragma unroll
        for (int i = 0; i < 2; i++)
#pragma unroll
            for (int j = 0; j < 4; j++)
                acc[i][j] = __builtin_amdgcn_mfma_f32_16x16x32_bf16(
                    aF[i], bF[j], acc[i][j], 0, 0, 0);
        SCHED_FENCE();
        BAR();
        cur ^= 1;
    }
}

// ---------------- output projection: 64x128 tiles, 384 blocks ----------------
__global__ __launch_bounds__(256) void gemm_out64(
    const u16* __restrict__ ob, const u16* __restrict__ wob,
    const float* __restrict__ bo, float* __restrict__ out) {
    __shared__ __align__(16) u16 a_lds[2 * 64 * 32];
    __shared__ __align__(16) u16 b_lds[2 * 128 * 32];
    const int m0 = blockIdx.x * 64, n0 = blockIdx.y * 128;
    f32x4 acc[2][4] = {};
    gemm_core64(ob, wob + n0 * 768, m0, a_lds, b_lds, acc);
    const int t = threadIdx.x, w = t >> 6, lane = t & 63, ln = lane & 15, lh = lane >> 4;
    const int wr = w >> 1, wc = w & 1;
#pragma unroll
    for (int j = 0; j < 4; j++) {
        int n = n0 + wc * 64 + j * 16 + ln;
        float bb = bo[n];
#pragma unroll
        for (int i = 0; i < 2; i++)
#pragma unroll
            for (int r = 0; r < 4; r++) {
                int m = m0 + wr * 32 + i * 16 + lh * 4 + r;
                out[m * 768 + n] = acc[i][j][r] + bb;
            }
    }
}

// ---------------- attention v9: TWO q-tiles per wave, shared K/V frags ----------
// 480 blocks = 24 bh x 20 (t7, piece). Wave w handles tiles (t7+8*w) and (t7+8*(w+4)):
// K-frag and V-frag LDS reads are shared between both tiles (same keys, different Q).
__global__ __launch_bounds__(256) void attn9(
    const u16* __restrict__ q_ws, const u16* __restrict__ k_ws,
    const u16* __restrict__ vt_ws, u16* __restrict__ o_ws,
    u16* __restrict__ po_ws, float* __restrict__ l_ws) {
    __shared__ __align__(16) u16 k_lds[2][64 * 64];   // [key][d], 16B units u^=key&7
    __shared__ __align__(16) u16 v_lds[2][64 * 64];   // [d][key], 16B units u^=d&7

    const int t = threadIdx.x, w = t >> 6, l = t & 63, lq = l & 31, H = l >> 5;
    int id = blockIdx.x;
    int bh8 = id & 7, idq = id >> 3;                  // XCD pin on bh%8
    int bhq = idq % 3, pg = idq / 3;                  // pg 0..19, heavy t7 first
    int t7, piece;
    if (pg < 4)       { t7 = 7; piece = pg; }
    else if (pg < 8)  { t7 = 6; piece = pg - 4; }
    else if (pg < 11) { t7 = 5; piece = pg - 8; }
    else if (pg < 14) { t7 = 4; piece = pg - 11; }
    else if (pg < 16) { t7 = 3; piece = pg - 14; }
    else if (pg < 18) { t7 = 2; piece = pg - 16; }
    else if (pg < 19) { t7 = 1; piece = 0; }
    else              { t7 = 0; piece = 0; }
    const int np = (t7 + 2) >> 1;                     // pieces per tile (8 iters each)
    const int bh = bhq * 8 + bh8;
    const int tiA = w, tiB = w + 4;
    const int qw0a = (t7 + 8 * tiA) * 32;
    const int qw0b = (t7 + 8 * tiB) * 32;

    const u16* Qb = q_ws + (size_t)bh * 2048 * 64;
    const u16* Kb = k_ws + (size_t)bh * 2048 * 64;
    const u16* Vt = vt_ws + (size_t)bh * 64 * 2048;

    // permuted K-row index (swap bits 2<->3 of lq)
    const int lqp = (lq & 19) | ((lq & 4) << 1) | ((lq & 8) >> 1);
    const int ksw = lqp & 7;
    const int vsw = lq & 7;

    bfrag qFa[4], qFb[4];
#pragma unroll
    for (int kd = 0; kd < 4; kd++) {
        qFa[kd] = *(const bfrag*)(Qb + (size_t)(qw0a + lq) * 64 + kd * 16 + H * 8);
        qFb[kd] = *(const bfrag*)(Qb + (size_t)(qw0b + lq) * 64 + kd * 16 + H * 8);
    }

    const f32x16 Z = {};
    f32x16 O0a = Z, O1a = Z, O0b = Z, O1b = Z;
    float lsa = 0.f, lsb = 0.f;

    const int skey = t >> 3;
    const int su = (t & 7) ^ (skey & 7);

    auto STAGE = [&](int k0, int bi) {
        glds16(Kb + (size_t)(k0 + skey) * 64 + su * 8,        k_lds[bi] + w * 512);
        glds16(Kb + (size_t)(k0 + skey + 32) * 64 + su * 8,   k_lds[bi] + 2048 + w * 512);
        glds16(Vt + (size_t)skey * 2048 + k0 + su * 8,        v_lds[bi] + w * 512);
        glds16(Vt + (size_t)(skey + 32) * 2048 + k0 + su * 8, v_lds[bi] + 2048 + w * 512);
    };

    int gp0 = piece * 8;
    int win = gp0 / np, pb = gp0 - win * np;
    STAGE(win * 256 + pb * 64, 0);

    for (int j = 0; j < 8; ++j) {
        int winn = win, pbn = pb + 1;
        if (pbn == np) { pbn = 0; winn = win + 1; }
        if (j < 7) {
            STAGE(winn * 256 + pbn * 64, (j + 1) & 1);
            WAIT_VM4();
        } else {
            WAIT_VM0();
        }
        BAR();
        SCHED_FENCE();

        const int cb = 2 * pb;
        const bool c1 = (cb + 1) <= t7, d0 = (cb == t7), d1 = (cb + 1 == t7);
        const u16* kl = k_lds[j & 1];
        const u16* vl = v_lds[j & 1];

        // S^T = K . Q for BOTH tiles (shared kf reads)
        PRIO(1);
        f32x16 s0a, s1a, s0b, s1b;
        {
            bfrag kf = *(const bfrag*)(kl + lqp * 64 + ((H) ^ ksw) * 8);
            s0a = mfma32(kf, qFa[0], Z);
            s0b = mfma32(kf, qFb[0], Z);
#pragma unroll
            for (int kd = 1; kd < 4; kd++) {
                bfrag k2 = *(const bfrag*)(kl + lqp * 64 + ((kd * 2 + H) ^ ksw) * 8);
                s0a = mfma32(k2, qFa[kd], s0a);
                s0b = mfma32(k2, qFb[kd], s0b);
            }
        }
        if (c1) {
            bfrag kf = *(const bfrag*)(kl + (32 + lqp) * 64 + ((H) ^ ksw) * 8);
            s1a = mfma32(kf, qFa[0], Z);
            s1b = mfma32(kf, qFb[0], Z);
#pragma unroll
            for (int kd = 1; kd < 4; kd++) {
                bfrag k2 = *(const bfrag*)(kl + (32 + lqp) * 64 + ((kd * 2 + H) ^ ksw) * 8);
                s1a = mfma32(k2, qFa[kd], s1a);
                s1b = mfma32(k2, qFb[kd], s1b);
            }
        }
        PRIO(0);

        // shared V-frags (read once, used by both tiles)
        bfrag v0[4], v1[4];
        {
            v0[0] = *(const bfrag*)(vl + lq * 64 + ((H) ^ vsw) * 8);
            v1[0] = *(const bfrag*)(vl + (32 + lq) * 64 + ((H) ^ vsw) * 8);
            v0[1] = *(const bfrag*)(vl + lq * 64 + ((2 + H) ^ vsw) * 8);
            v1[1] = *(const bfrag*)(vl + (32 + lq) * 64 + ((2 + H) ^ vsw) * 8);
            if (c1) {
                v0[2] = *(const bfrag*)(vl + lq * 64 + ((4 + H) ^ vsw) * 8);
                v1[2] = *(const bfrag*)(vl + (32 + lq) * 64 + ((4 + H) ^ vsw) * 8);
                v0[3] = *(const bfrag*)(vl + lq * 64 + ((6 + H) ^ vsw) * 8);
                v1[3] = *(const bfrag*)(vl + (32 + lq) * 64 + ((6 + H) ^ vsw) * 8);
            }
        }

        // ---- tile A: softmax + PV ----
        {
            float ps = 0.f;
            u32 pkA[8], pkB[8];
            if (d0) {
#pragma unroll
                for (int r2 = 0; r2 < 16; r2++) {
                    int ka = (r2 & 3) + 4 * ((r2 >> 2) & 1) + 16 * (r2 >> 3) + 8 * H;
                    if (ka > lq) s0a[r2] = -1e30f;
                }
            }
#pragma unroll
            for (int i = 0; i < 8; i++) {
                float a = exp2f(s0a[2 * i]), b2 = exp2f(s0a[2 * i + 1]);
                ps += a + b2; pkA[i] = cvt_pk_bf16(a, b2);
            }
            if (c1) {
                if (d1) {
#pragma unroll
                    for (int r2 = 0; r2 < 16; r2++) {
                        int ka = (r2 & 3) + 4 * ((r2 >> 2) & 1) + 16 * (r2 >> 3) + 8 * H;
                        if (ka > lq) s1a[r2] = -1e30f;
                    }
                }
#pragma unroll
                for (int i = 0; i < 8; i++) {
                    float a = exp2f(s1a[2 * i]), b2 = exp2f(s1a[2 * i + 1]);
                    ps += a + b2; pkB[i] = cvt_pk_bf16(a, b2);
                }
            }
            lsa += ps;
            PRIO(1);
            {
                u32x4 a0 = {pkA[0], pkA[1], pkA[2], pkA[3]};
                u32x4 a1 = {pkA[4], pkA[5], pkA[6], pkA[7]};
                bfrag A0 = __builtin_bit_cast(bfrag, a0);
                bfrag A1 = __builtin_bit_cast(bfrag, a1);
                O0a = mfma32(A0, v0[0], O0a);
                O1a = mfma32(A0, v1[0], O1a);
                O0a = mfma32(A1, v0[1], O0a);
                O1a = mfma32(A1, v1[1], O1a);
            }
            if (c1) {
                u32x4 a0 = {pkB[0], pkB[1], pkB[2], pkB[3]};
                u32x4 a1 = {pkB[4], pkB[5], pkB[6], pkB[7]};
                bfrag A0 = __builtin_bit_cast(bfrag, a0);
                bfrag A1 = __builtin_bit_cast(bfrag, a1);
                O0a = mfma32(A0, v0[2], O0a);
                O1a = mfma32(A0, v1[2], O1a);
                O0a = mfma32(A1, v0[3], O0a);
                O1a = mfma32(A1, v1[3], O1a);
            }
            PRIO(0);
        }

        // ---- tile B: softmax + PV ----
        {
            float ps = 0.f;
            u32 pkA[8], pkB[8];
            if (d0) {
#pragma unroll
                for (int r2 = 0; r2 < 16; r2++) {
                    int ka = (r2 & 3) + 4 * ((r2 >> 2) & 1) + 16 * (r2 >> 3) + 8 * H;
                    if (ka > lq) s0b[r2] = -1e30f;
                }
            }
#pragma unroll
            for (int i = 0; i < 8; i++) {
                float a = exp2f(s0b[2 * i]), b2 = exp2f(s0b[2 * i + 1]);
                ps += a + b2; pkA[i] = cvt_pk_bf16(a, b2);
            }
            if (c1) {
                if (d1) {
#pragma unroll
                    for (int r2 = 0; r2 < 16; r2++) {
                        int ka = (r2 & 3) + 4 * ((r2 >> 2) & 1) + 16 * (r2 >> 3) + 8 * H;
                        if (ka > lq) s1b[r2] = -1e30f;
                    }
                }
#pragma unroll
                for (int i = 0; i < 8; i++) {
                    float a = exp2f(s1b[2 * i]), b2 = exp2f(s1b[2 * i + 1]);
                    ps += a + b2; pkB[i] = cvt_pk_bf16(a, b2);
                }
            }
            lsb += ps;
            PRIO(1);
            {
                u32x4 a0 = {pkA[0], pkA[1], pkA[2], pkA[3]};
                u32x4 a1 = {pkA[4], pkA[5], pkA[6], pkA[7]};
                bfrag A0 = __builtin_bit_cast(bfrag, a0);
                bfrag A1 = __builtin_bit_cast(bfrag, a1);
                O0b = mfma32(A0, v0[0], O0b);
                O1b = mfma32(A0, v1[0], O1b);
                O0b = mfma32(A1, v0[1], O0b);
                O1b = mfma32(A1, v1[1], O1b);
            }
            if (c1) {
                u32x4 a0 = {pkB[0], pkB[1], pkB[2], pkB[3]};
                u32x4 a1 = {pkB[4], pkB[5], pkB[6], pkB[7]};
                bfrag A0 = __builtin_bit_cast(bfrag, a0);
                bfrag A1 = __builtin_bit_cast(bfrag, a1);
                O0b = mfma32(A0, v0[2], O0b);
                O1b = mfma32(A0, v1[2], O1b);
                O0b = mfma32(A1, v0[3], O0b);
                O1b = mfma32(A1, v1[3], O1b);
            }
            PRIO(0);
        }

        SCHED_FENCE();
        BAR();
        win = winn; pb = pbn;
    }

    const int cum8[8] = {0, 8, 16, 32, 48, 72, 96, 128};
    const int b = bh / 12, h = bh % 12;
    float lsTa = lsa + __shfl_xor(lsa, 32);
    float lsTb = lsb + __shfl_xor(lsb, 32);
    if (np == 1) {
        float liva = 1.f / lsTa, livb = 1.f / lsTb;
#pragma unroll
        for (int r2 = 0; r2 < 16; r2++) {
            int row = (r2 & 3) + 8 * (r2 >> 2) + 4 * H;
            float fra = __shfl(liva, row);
            float frb = __shfl(livb, row);
            size_t ba = ((size_t)(b * 2048 + qw0a + row)) * 768 + h * 64;
            size_t bb2 = ((size_t)(b * 2048 + qw0b + row)) * 768 + h * 64;
            o_ws[ba + lq] = f2bf(O0a[r2] * fra);
            o_ws[ba + 32 + lq] = f2bf(O1a[r2] * fra);
            o_ws[bb2 + lq] = f2bf(O0b[r2] * frb);
            o_ws[bb2 + 32 + lq] = f2bf(O1b[r2] * frb);
        }
    } else {
        size_t pa = (size_t)bh * 160 + cum8[t7] + tiA * np + piece;
        size_t pbx = (size_t)bh * 160 + cum8[t7] + tiB * np + piece;
        u16* poa = po_ws + pa * 2048;
        u16* pob = po_ws + pbx * 2048;
#pragma unroll
        for (int r2 = 0; r2 < 16; r2++) {
            int row = (r2 & 3) + 8 * (r2 >> 2) + 4 * H;
            poa[row * 64 + lq] = f2bf(O0a[r2]);
            poa[row * 64 + 32 + lq] = f2bf(O1a[r2]);
            pob[row * 64 + lq] = f2bf(O0b[r2]);
            pob[row * 64 + 32 + lq] = f2bf(O1b[r2]);
        }
        if (l < 32) {
            l_ws[pa * 32 + lq] = lsTa;
            l_ws[pbx * 32 + lq] = lsTb;
        }
    }
}

// ---------------- combine partial O pieces (t7 >= 2 tiles only) ----------------
__global__ __launch_bounds__(256) void combine_o(
    const u16* __restrict__ po_ws, const float* __restrict__ l_ws,
    u16* __restrict__ o_ws) {
    int id = blockIdx.x;                              // 1152 = 24 bh x 48 tiles (t7>=2)
    int bh8 = id & 7, idq = id >> 3;
    int bhq = idq % 3, r = idq / 3;
    int bh = bhq * 8 + bh8;
    int t7 = 2 + (r >> 3), ti = r & 7;
    int tile = t7 + 8 * ti;
    int np = (t7 + 2) >> 1;
    const int cum8[8] = {0, 8, 16, 32, 48, 72, 96, 128};
    size_t base = (size_t)bh * 160 + cum8[t7] + ti * np;
    int t = threadIdx.x;
    int q = t >> 3, d8 = (t & 7) * 8;
    float acc[8] = {0.f, 0.f, 0.f, 0.f, 0.f, 0.f, 0.f, 0.f};
    float lt = 0.f;
    for (int i = 0; i < np; i++) {
        lt += l_ws[(base + i) * 32 + q];
        bfrag v = *(const bfrag*)(po_ws + (base + i) * 2048 + q * 64 + d8);
#pragma unroll
        for (int e = 0; e < 8; e++)
            acc[e] += __uint_as_float(((u32)(u16)v[e]) << 16);
    }
    float inv = 1.f / lt;
    u32x4 pkv;
#pragma unroll
    for (int e = 0; e < 4; e++)
        pkv[e] = cvt_pk_bf16(acc[2 * e] * inv, acc[2 * e + 1] * inv);
    int b = bh / 12, h = bh % 12;
    size_t dst = ((size_t)(b * 2048 + tile * 32 + q)) * 768 + h * 64 + d8;
    *(u32x4*)(o_ws + dst) = pkv;
}

// ---------------- launcher ----------------
extern "C" void kernel_launch(void* const* d_in, const int* in_sizes, int n_in,
                              void* d_out, int out_size, void* d_ws, size_t ws_size,
                              hipStream_t stream) {
    const float* x  = (const float*)d_in[0];
    const float* Wq = (const float*)d_in[1];
    const float* bq = (const float*)d_in[2];
    const float* Wk = (const float*)d_in[3];
    const float* bk = (const float*)d_in[4];
    const float* Wv = (const float*)d_in[5];
    const float* bv = (const float*)d_in[6];
    const float* Wo = (const float*)d_in[7];
    const float* bo = (const float*)d_in[8];
    float* out = (float*)d_out;

    char* p = (char*)d_ws;
    u16*   q_ws  = (u16*)(p + 0);
    u16*   k_ws  = (u16*)(p + 6291456);
    u16*   vt_ws = (u16*)(p + 12582912);
    u16*   po_ws = (u16*)(p + 18874368);
    u16*   xb    = (u16*)(p + 18874368);              // overlay
    u16*   wqb   = (u16*)(p + 25165824);
    u16*   wkb   = (u16*)(p + 26345472);
    u16*   wvb   = (u16*)(p + 27525120);
    float* l_ws  = (float*)(p + 34603008);
    u16*   wob   = (u16*)(p + 35094528);
    u16*   o_ws  = (u16*)(p + 36274176);

    convert_all<<<5376, 256, 0, stream>>>(x, Wq, Wk, Wv, Wo, xb, wqb, wkb, wvb, wob);
    gemm_qkv<<<dim3(32, 18), 256, 0, stream>>>(xb, wqb, wkb, wvb, bq, bk, bv, q_ws, k_ws, vt_ws);
    attn9<<<dim3(480), 256, 0, stream>>>(q_ws, k_ws, vt_ws, o_ws, po_ws, l_ws);
    combine_o<<<dim3(1152), 256, 0, stream>>>(po_ws, l_ws, o_ws);
    gemm_out64<<<dim3(64, 6), 256, 0, stream>>>(o_ws, wob, bo, out);
}

// Round 12
// 85.187 us; speedup vs baseline: 1.1780x; 1.1780x over previous
//
#include <hip/hip_runtime.h>

typedef unsigned short u16;
typedef unsigned int u32;
typedef unsigned long long u64;
typedef __attribute__((ext_vector_type(8))) short bfrag;    // 8 bf16 = 4 VGPRs
typedef __attribute__((ext_vector_type(4))) float f32x4;
typedef __attribute__((ext_vector_type(16))) float f32x16;
typedef __attribute__((ext_vector_type(4))) u32 u32x4;

#define QSCALE 0.18033688f   // 0.125 * log2(e): scores land in log2 domain

__device__ __forceinline__ u16 f2bf(float f) {
    unsigned u = __float_as_uint(f);
    u += 0x7FFFu + ((u >> 16) & 1u);           // RNE
    return (u16)(u >> 16);
}

__device__ __forceinline__ u32 cvt_pk_bf16(float lo, float hi) {
    u32 r;
    asm("v_cvt_pk_bf16_f32 %0, %1, %2" : "=v"(r) : "v"(lo), "v"(hi));
    return r;
}

// native 2^x (v_exp_f32). exp2f() without fast-math lowers to the guarded OCML
// libm routine (~20+ VALU insts); this is the single-instruction version.
__device__ __forceinline__ float fexp2(float x) {
    float r;
    asm("v_exp_f32 %0, %1" : "=v"(r) : "v"(x));
    return r;
}

__device__ __forceinline__ void glds16(const void* g, void* l) {
    __builtin_amdgcn_global_load_lds((__attribute__((address_space(1))) void*)g,
                                     (__attribute__((address_space(3))) void*)l,
                                     16, 0, 0);
}

__device__ __forceinline__ f32x16 mfma32(bfrag a, bfrag b, f32x16 c) {
    return __builtin_amdgcn_mfma_f32_32x32x16_bf16(a, b, c, 0, 0, 0);
}

#define WAIT_VM4()  asm volatile("s_waitcnt vmcnt(4)" ::: "memory")
#define WAIT_VM3()  asm volatile("s_waitcnt vmcnt(3)" ::: "memory")
#define WAIT_VM0()  asm volatile("s_waitcnt vmcnt(0)" ::: "memory")
#define BAR()       __builtin_amdgcn_s_barrier()
#define SCHED_FENCE() __builtin_amdgcn_sched_barrier(0)
#define PRIO(n)     __builtin_amdgcn_s_setprio(n)

// ---------------- convert: fp32 -> bf16 for x, Wq, Wk, Wv, Wo ----------------
__global__ __launch_bounds__(256) void convert_all(
    const float* __restrict__ x, const float* __restrict__ wq,
    const float* __restrict__ wk, const float* __restrict__ wv,
    const float* __restrict__ wo,
    u16* __restrict__ xb, u16* __restrict__ wqb, u16* __restrict__ wkb,
    u16* __restrict__ wvb, u16* __restrict__ wob) {
    const int XV = (2 * 2048 * 768) / 4;
    const int WV = (768 * 768) / 4;
    int i = blockIdx.x * 256 + threadIdx.x;
    if (i >= XV + 4 * WV) return;
    const float4* src; u16* dst; int off;
    if (i < XV) { src = (const float4*)x; dst = xb; off = i; }
    else {
        int j = i - XV; int z = j / WV; off = j - z * WV;
        src = (const float4*)(z == 0 ? wq : z == 1 ? wk : z == 2 ? wv : wo);
        dst = (z == 0 ? wqb : z == 1 ? wkb : z == 2 ? wvb : wob);
    }
    float4 v = src[off];
    u64 pk = (u64)f2bf(v.x)
        | ((u64)f2bf(v.y) << 16)
        | ((u64)f2bf(v.z) << 32)
        | ((u64)f2bf(v.w) << 48);
    *(u64*)(dst + off * 4) = pk;
}

// ---------------- GEMM core 128x128 (R8 version) ----------------
__device__ __forceinline__ void gemm_core(
    const u16* __restrict__ A, const u16* __restrict__ Bw, int m0,
    u16* a_lds, u16* b_lds, f32x4 acc[4][4]) {
    const int t = threadIdx.x;
    const int w = t >> 6, lane = t & 63, ln = lane & 15, lh = lane >> 4;
    const int wr = w >> 1, wc = w & 1;

    const int row0 = t >> 2;
    const int u0 = (t & 3) ^ ((row0 >> 1) & 3);
    const int row1 = row0 + 64;
    const int u1 = (t & 3) ^ ((row1 >> 1) & 3);
    const u16* ga0 = A + (m0 + row0) * 768 + u0 * 8;
    const u16* ga1 = A + (m0 + row1) * 768 + u1 * 8;
    const u16* gb0 = Bw + row0 * 768 + u0 * 8;
    const u16* gb1 = Bw + row1 * 768 + u1 * 8;
    u16* la = a_lds + w * 512;
    u16* lb = b_lds + w * 512;

    auto STAGE = [&](int k0, int bi) {
        glds16(ga0 + k0, la + bi * 4096);
        glds16(ga1 + k0, la + bi * 4096 + 2048);
        glds16(gb0 + k0, lb + bi * 4096);
        glds16(gb1 + k0, lb + bi * 4096 + 2048);
    };

    STAGE(0, 0);
    int cur = 0;
    for (int k0 = 0; k0 < 768; k0 += 32) {
        if (k0 + 32 < 768) {
            STAGE(k0 + 32, cur ^ 1);
            WAIT_VM4();
        } else {
            WAIT_VM0();
        }
        BAR();
        SCHED_FENCE();
        const u16* ab = a_lds + cur * 4096;
        const u16* bb = b_lds + cur * 4096;
        bfrag aF[4], bF[4];
#pragma unroll
        for (int i = 0; i < 4; i++) {
            int ra = wr * 64 + i * 16 + ln;
            aF[i] = *(const bfrag*)(ab + ra * 32 + ((lh ^ ((ra >> 1) & 3)) * 8));
            int rb = wc * 64 + i * 16 + ln;
            bF[i] = *(const bfrag*)(bb + rb * 32 + ((lh ^ ((rb >> 1) & 3)) * 8));
        }
#pragma unroll
        for (int i = 0; i < 4; i++)
#pragma unroll
            for (int j = 0; j < 4; j++)
                acc[i][j] = __builtin_amdgcn_mfma_f32_16x16x32_bf16(
                    aF[i], bF[j], acc[i][j], 0, 0, 0);
        SCHED_FENCE();
        BAR();
        cur ^= 1;
    }
}

// ---------------- QKV projection (128x128) ----------------
__global__ __launch_bounds__(256) void gemm_qkv(
    const u16* __restrict__ xb,
    const u16* __restrict__ wqb, const u16* __restrict__ wkb, const u16* __restrict__ wvb,
    const float* __restrict__ bq, const float* __restrict__ bk, const float* __restrict__ bv,
    u16* __restrict__ q_ws, u16* __restrict__ k_ws, u16* __restrict__ vt_ws) {
    __shared__ __align__(16) u16 smem[16384];         // a_lds 8192 | b_lds 8192
    u16* a_lds = smem;
    u16* b_lds = smem + 8192;
    const int m0 = blockIdx.x * 128;
    const int z = blockIdx.y / 6, nb = blockIdx.y % 6;
    const u16* Bw = (z == 0 ? wqb : z == 1 ? wkb : wvb) + nb * 128 * 768;
    const float* bias = (z == 0 ? bq : z == 1 ? bk : bv);

    f32x4 acc[4][4] = {};
    gemm_core(xb, Bw, m0, a_lds, b_lds, acc);

    const int t = threadIdx.x, w = t >> 6, lane = t & 63, ln = lane & 15, lh = lane >> 4;
    const int wr = w >> 1, wc = w & 1;
    if (z == 2) {
        // ---- LDS transpose: T[n=128][m=128] u16, 16B units swizzled by n ----
        __syncthreads();
        char* T = (char*)smem;
#pragma unroll
        for (int j = 0; j < 4; j++) {
            int nt = wc * 64 + j * 16 + ln;
            float bb = bias[nb * 128 + nt];
#pragma unroll
            for (int i = 0; i < 4; i++) {
                int m0t = wr * 64 + i * 16 + lh * 4;
                u64 pk = (u64)f2bf(acc[i][j][0] + bb)
                    | ((u64)f2bf(acc[i][j][1] + bb) << 16)
                    | ((u64)f2bf(acc[i][j][2] + bb) << 32)
                    | ((u64)f2bf(acc[i][j][3] + bb) << 48);
                int off = nt * 256 + ((m0t * 2) ^ ((nt & 15) << 4));
                *(u64*)(T + off) = pk;
            }
        }
        __syncthreads();
        const int b = m0 >> 11, s0 = m0 & 2047;
#pragma unroll
        for (int c = 0; c < 8; c++) {
            int g = c * 256 + t;
            int nt = g >> 4, mc = (g & 15) * 8;
            int off = nt * 256 + ((mc * 2) ^ ((nt & 15) << 4));
            u32x4 v = *(const u32x4*)(T + off);
            int nl = nb * 128 + nt;
            int h = nl >> 6, d = nl & 63;
            *(u32x4*)(vt_ws + ((size_t)((b * 12 + h) * 64 + d)) * 2048 + s0 + mc) = v;
        }
    } else {
        u16* dst = (z == 0 ? q_ws : k_ws);
        const float sc = (z == 0) ? QSCALE : 1.0f;
#pragma unroll
        for (int j = 0; j < 4; j++) {
            int nl = nb * 128 + wc * 64 + j * 16 + ln;
            int h = nl >> 6, d = nl & 63;
            float bb = bias[nl];
#pragma unroll
            for (int i = 0; i < 4; i++)
#pragma unroll
                for (int r = 0; r < 4; r++) {
                    int m = m0 + wr * 64 + i * 16 + lh * 4 + r;
                    int b = m >> 11, s = m & 2047;
                    dst[((size_t)((b * 12 + h) * 2048 + s)) * 64 + d] = f2bf((acc[i][j][r] + bb) * sc);
                }
        }
    }
}

// ---------------- GEMM core 64x128 (for output projection) ----------------
__device__ __forceinline__ void gemm_core64(
    const u16* __restrict__ A, const u16* __restrict__ Bw, int m0,
    u16* a_lds, u16* b_lds, f32x4 acc[2][4]) {
    const int t = threadIdx.x;
    const int w = t >> 6, lane = t & 63, ln = lane & 15, lh = lane >> 4;
    const int wr = w >> 1, wc = w & 1;

    const int rowA = t >> 2;
    const int uA = (t & 3) ^ ((rowA >> 1) & 3);
    const int rowB1 = rowA + 64;
    const int uB1 = (t & 3) ^ ((rowB1 >> 1) & 3);
    const u16* ga  = A + (m0 + rowA) * 768 + uA * 8;
    const u16* gb0 = Bw + rowA * 768 + uA * 8;
    const u16* gb1 = Bw + rowB1 * 768 + uB1 * 8;
    u16* la = a_lds + w * 512;
    u16* lb = b_lds + w * 512;

    auto STAGE = [&](int k0, int bi) {
        glds16(ga + k0, la + bi * 2048);
        glds16(gb0 + k0, lb + bi * 4096);
        glds16(gb1 + k0, lb + bi * 4096 + 2048);
    };

    STAGE(0, 0);
    int cur = 0;
    for (int k0 = 0; k0 < 768; k0 += 32) {
        if (k0 + 32 < 768) {
            STAGE(k0 + 32, cur ^ 1);
            WAIT_VM3();
        } else {
            WAIT_VM0();
        }
        BAR();
        SCHED_FENCE();
        const u16* ab = a_lds + cur * 2048;
        const u16* bb = b_lds + cur * 4096;
        bfrag aF[2], bF[4];
#pragma unroll
        for (int i = 0; i < 2; i++) {
            int ra = wr * 32 + i * 16 + ln;
            aF[i] = *(const bfrag*)(ab + ra * 32 + ((lh ^ ((ra >> 1) & 3)) * 8));
        }
#pragma unroll
        for (int j = 0; j < 4; j++) {
            int rb = wc * 64 + j * 16 + ln;
            bF[j] = *(const bfrag*)(bb + rb * 32 + ((lh ^ ((rb >> 1) & 3)) * 8));
        }
#pragma unroll
        for (int i = 0; i < 2; i++)
#pragma unroll
            for (int j = 0; j < 4; j++)
                acc[i][j] = __builtin_amdgcn_mfma_f32_16x16x32_bf16(
                    aF[i], bF[j], acc[i][j], 0, 0, 0);
        SCHED_FENCE();
        BAR();
        cur ^= 1;
    }
}

// ---------------- output projection: 64x128 tiles, 384 blocks ----------------
__global__ __launch_bounds__(256) void gemm_out64(
    const u16* __restrict__ ob, const u16* __restrict__ wob,
    const float* __restrict__ bo, float* __restrict__ out) {
    __shared__ __align__(16) u16 a_lds[2 * 64 * 32];
    __shared__ __align__(16) u16 b_lds[2 * 128 * 32];
    const int m0 = blockIdx.x * 64, n0 = blockIdx.y * 128;
    f32x4 acc[2][4] = {};
    gemm_core64(ob, wob + n0 * 768, m0, a_lds, b_lds, acc);
    const int t = threadIdx.x, w = t >> 6, lane = t & 63, ln = lane & 15, lh = lane >> 4;
    const int wr = w >> 1, wc = w & 1;
#pragma unroll
    for (int j = 0; j < 4; j++) {
        int n = n0 + wc * 64 + j * 16 + ln;
        float bb = bo[n];
#pragma unroll
        for (int i = 0; i < 2; i++)
#pragma unroll
            for (int r = 0; r < 4; r++) {
                int m = m0 + wr * 32 + i * 16 + lh * 4 + r;
                out[m * 768 + n] = acc[i][j][r] + bb;
            }
    }
}

// ---------------- attention v10: R8 structure + native v_exp_f32 softmax ----------
__global__ __launch_bounds__(256) void attn10(
    const u16* __restrict__ q_ws, const u16* __restrict__ k_ws,
    const u16* __restrict__ vt_ws, u16* __restrict__ o_ws,
    u16* __restrict__ po_ws, float* __restrict__ l_ws) {
    __shared__ __align__(16) u16 k_lds[2][64 * 64];   // [key][d], 16B units u^=key&7
    __shared__ __align__(16) u16 v_lds[2][64 * 64];   // [d][key], 16B units u^=d&7

    const int t = threadIdx.x, w = t >> 6, l = t & 63, lq = l & 31, H = l >> 5;
    int id = blockIdx.x;
    int bh8 = id & 7, idq = id >> 3;                  // XCD pin on bh%8
    int bhq = idq % 3, pg = idq / 3;                  // pg 0..39, heavy t7 first
    int t7, rem;
    if (pg < 16)      { t7 = 7 - (pg >> 3); rem = pg & 7; }
    else if (pg < 28) { int u = pg - 16; t7 = 5 - u / 6; rem = u % 6; }
    else if (pg < 36) { int u = pg - 28; t7 = 3 - (u >> 2); rem = u & 3; }
    else              { int u = pg - 36; t7 = 1 - (u >> 1); rem = u & 1; }
    const int np = (t7 + 2) >> 1;                     // pieces per tile (8 iters each)
    const int quad = rem / np, piece = rem - quad * np;
    const int bh = bhq * 8 + bh8;
    const int ti = quad * 4 + w;
    const int tile = t7 + 8 * ti;
    const int qw0 = tile * 32;

    const u16* Qb = q_ws + (size_t)bh * 2048 * 64;
    const u16* Kb = k_ws + (size_t)bh * 2048 * 64;
    const u16* Vt = vt_ws + (size_t)bh * 64 * 2048;

    // permuted K-row index (swap bits 2<->3 of lq)
    const int lqp = (lq & 19) | ((lq & 4) << 1) | ((lq & 8) >> 1);
    const int ksw = lqp & 7;
    const int vsw = lq & 7;

    bfrag qF[4];
#pragma unroll
    for (int kd = 0; kd < 4; kd++)
        qF[kd] = *(const bfrag*)(Qb + (size_t)(qw0 + lq) * 64 + kd * 16 + H * 8);

    const f32x16 Z = {};
    f32x16 O0 = Z, O1 = Z;
    float lsum = 0.f;

    const int skey = t >> 3;
    const int su = (t & 7) ^ (skey & 7);

    auto STAGE = [&](int k0, int bi) {
        glds16(Kb + (size_t)(k0 + skey) * 64 + su * 8,        k_lds[bi] + w * 512);
        glds16(Kb + (size_t)(k0 + skey + 32) * 64 + su * 8,   k_lds[bi] + 2048 + w * 512);
        glds16(Vt + (size_t)skey * 2048 + k0 + su * 8,        v_lds[bi] + w * 512);
        glds16(Vt + (size_t)(skey + 32) * 2048 + k0 + su * 8, v_lds[bi] + 2048 + w * 512);
    };

    int gp0 = piece * 8;
    int win = gp0 / np, pb = gp0 - win * np;
    STAGE(win * 256 + pb * 64, 0);

    for (int j = 0; j < 8; ++j) {
        int winn = win, pbn = pb + 1;
        if (pbn == np) { pbn = 0; winn = win + 1; }
        if (j < 7) {
            STAGE(winn * 256 + pbn * 64, (j + 1) & 1);
            WAIT_VM4();
        } else {
            WAIT_VM0();
        }
        BAR();
        SCHED_FENCE();

        const int cb = 2 * pb;
        const bool c1 = (cb + 1) <= t7, d0 = (cb == t7), d1 = (cb + 1 == t7);
        const u16* kl = k_lds[j & 1];
        const u16* vl = v_lds[j & 1];

        // S^T = K . Q with permuted key rows
        PRIO(1);
        f32x16 s0, s1;
        {
            bfrag kf = *(const bfrag*)(kl + lqp * 64 + ((H) ^ ksw) * 8);
            s0 = mfma32(kf, qF[0], Z);
#pragma unroll
            for (int kd = 1; kd < 4; kd++) {
                bfrag k2 = *(const bfrag*)(kl + lqp * 64 + ((kd * 2 + H) ^ ksw) * 8);
                s0 = mfma32(k2, qF[kd], s0);
            }
        }
        if (c1) {
            bfrag kf = *(const bfrag*)(kl + (32 + lqp) * 64 + ((H) ^ ksw) * 8);
            s1 = mfma32(kf, qF[0], Z);
#pragma unroll
            for (int kd = 1; kd < 4; kd++) {
                bfrag k2 = *(const bfrag*)(kl + (32 + lqp) * 64 + ((kd * 2 + H) ^ ksw) * 8);
                s1 = mfma32(k2, qF[kd], s1);
            }
        }
        PRIO(0);

        // fixed-scale softmax: p = 2^s via native v_exp; diagonal masked
        float ps = 0.f;
        u32 pkA[8], pkB[8];
        if (d0) {
#pragma unroll
            for (int r2 = 0; r2 < 16; r2++) {
                int ka = (r2 & 3) + 4 * ((r2 >> 2) & 1) + 16 * (r2 >> 3) + 8 * H;
                if (ka > lq) s0[r2] = -1e30f;
            }
        }
#pragma unroll
        for (int i = 0; i < 8; i++) {
            float a = fexp2(s0[2 * i]), b2 = fexp2(s0[2 * i + 1]);
            ps += a + b2; pkA[i] = cvt_pk_bf16(a, b2);
        }
        if (c1) {
            if (d1) {
#pragma unroll
                for (int r2 = 0; r2 < 16; r2++) {
                    int ka = (r2 & 3) + 4 * ((r2 >> 2) & 1) + 16 * (r2 >> 3) + 8 * H;
                    if (ka > lq) s1[r2] = -1e30f;
                }
            }
#pragma unroll
            for (int i = 0; i < 8; i++) {
                float a = fexp2(s1[2 * i]), b2 = fexp2(s1[2 * i + 1]);
                ps += a + b2; pkB[i] = cvt_pk_bf16(a, b2);
            }
        }
        lsum += ps;                                   // cross-half reduce deferred

        // PV: A-frags direct from pk words (zero shuffle); B = contiguous V runs
        PRIO(1);
        {
            u32x4 a0 = {pkA[0], pkA[1], pkA[2], pkA[3]};
            u32x4 a1 = {pkA[4], pkA[5], pkA[6], pkA[7]};
            bfrag A0 = __builtin_bit_cast(bfrag, a0);
            bfrag A1 = __builtin_bit_cast(bfrag, a1);
            bfrag v00 = *(const bfrag*)(vl + lq * 64 + ((H) ^ vsw) * 8);
            bfrag v01 = *(const bfrag*)(vl + (32 + lq) * 64 + ((H) ^ vsw) * 8);
            bfrag v10 = *(const bfrag*)(vl + lq * 64 + ((2 + H) ^ vsw) * 8);
            bfrag v11 = *(const bfrag*)(vl + (32 + lq) * 64 + ((2 + H) ^ vsw) * 8);
            O0 = mfma32(A0, v00, O0);
            O1 = mfma32(A0, v01, O1);
            O0 = mfma32(A1, v10, O0);
            O1 = mfma32(A1, v11, O1);
        }
        if (c1) {
            u32x4 a0 = {pkB[0], pkB[1], pkB[2], pkB[3]};
            u32x4 a1 = {pkB[4], pkB[5], pkB[6], pkB[7]};
            bfrag A0 = __builtin_bit_cast(bfrag, a0);
            bfrag A1 = __builtin_bit_cast(bfrag, a1);
            bfrag v00 = *(const bfrag*)(vl + lq * 64 + ((4 + H) ^ vsw) * 8);
            bfrag v01 = *(const bfrag*)(vl + (32 + lq) * 64 + ((4 + H) ^ vsw) * 8);
            bfrag v10 = *(const bfrag*)(vl + lq * 64 + ((6 + H) ^ vsw) * 8);
            bfrag v11 = *(const bfrag*)(vl + (32 + lq) * 64 + ((6 + H) ^ vsw) * 8);
            O0 = mfma32(A0, v00, O0);
            O1 = mfma32(A0, v01, O1);
            O0 = mfma32(A1, v10, O0);
            O1 = mfma32(A1, v11, O1);
        }
        PRIO(0);
        SCHED_FENCE();
        BAR();
        win = winn; pb = pbn;
    }

    float lsT = lsum + __shfl_xor(lsum, 32);
    if (np == 1) {
        // single piece == full tile: normalize and write o directly
        float linv = 1.f / lsT;
        const int b = bh / 12, h = bh % 12;
#pragma unroll
        for (int r2 = 0; r2 < 16; r2++) {
            int row = (r2 & 3) + 8 * (r2 >> 2) + 4 * H;
            float fr = __shfl(linv, row);
            size_t base = ((size_t)(b * 2048 + qw0 + row)) * 768 + h * 64;
            o_ws[base + lq] = f2bf(O0[r2] * fr);
            o_ws[base + 32 + lq] = f2bf(O1[r2] * fr);
        }
    } else {
        // partial store: po[q][d] bf16 + l (combine normalizes)
        const int cum8[8] = {0, 8, 16, 32, 48, 72, 96, 128};
        size_t pidx = (size_t)bh * 160 + cum8[t7] + ti * np + piece;
        u16* po = po_ws + pidx * 2048;
#pragma unroll
        for (int r2 = 0; r2 < 16; r2++) {
            int row = (r2 & 3) + 8 * (r2 >> 2) + 4 * H;   // query row (unpermuted)
            po[row * 64 + lq] = f2bf(O0[r2]);
            po[row * 64 + 32 + lq] = f2bf(O1[r2]);
        }
        if (l < 32) l_ws[pidx * 32 + lq] = lsT;
    }
}

// ---------------- combine partial O pieces (t7 >= 2 tiles only) ----------------
__global__ __launch_bounds__(256) void combine_o(
    const u16* __restrict__ po_ws, const float* __restrict__ l_ws,
    u16* __restrict__ o_ws) {
    int id = blockIdx.x;                              // 1152 = 24 bh x 48 tiles (t7>=2)
    int bh8 = id & 7, idq = id >> 3;
    int bhq = idq % 3, r = idq / 3;
    int bh = bhq * 8 + bh8;
    int t7 = 2 + (r >> 3), ti = r & 7;
    int tile = t7 + 8 * ti;
    int np = (t7 + 2) >> 1;
    const int cum8[8] = {0, 8, 16, 32, 48, 72, 96, 128};
    size_t base = (size_t)bh * 160 + cum8[t7] + ti * np;
    int t = threadIdx.x;
    int q = t >> 3, d8 = (t & 7) * 8;
    float acc[8] = {0.f, 0.f, 0.f, 0.f, 0.f, 0.f, 0.f, 0.f};
    float lt = 0.f;
    for (int i = 0; i < np; i++) {
        lt += l_ws[(base + i) * 32 + q];
        bfrag v = *(const bfrag*)(po_ws + (base + i) * 2048 + q * 64 + d8);
#pragma unroll
        for (int e = 0; e < 8; e++)
            acc[e] += __uint_as_float(((u32)(u16)v[e]) << 16);
    }
    float inv = 1.f / lt;
    u32x4 pkv;
#pragma unroll
    for (int e = 0; e < 4; e++)
        pkv[e] = cvt_pk_bf16(acc[2 * e] * inv, acc[2 * e + 1] * inv);
    int b = bh / 12, h = bh % 12;
    size_t dst = ((size_t)(b * 2048 + tile * 32 + q)) * 768 + h * 64 + d8;
    *(u32x4*)(o_ws + dst) = pkv;
}

// ---------------- launcher ----------------
extern "C" void kernel_launch(void* const* d_in, const int* in_sizes, int n_in,
                              void* d_out, int out_size, void* d_ws, size_t ws_size,
                              hipStream_t stream) {
    const float* x  = (const float*)d_in[0];
    const float* Wq = (const float*)d_in[1];
    const float* bq = (const float*)d_in[2];
    const float* Wk = (const float*)d_in[3];
    const float* bk = (const float*)d_in[4];
    const float* Wv = (const float*)d_in[5];
    const float* bv = (const float*)d_in[6];
    const float* Wo = (const float*)d_in[7];
    const float* bo = (const float*)d_in[8];
    float* out = (float*)d_out;

    char* p = (char*)d_ws;
    u16*   q_ws  = (u16*)(p + 0);
    u16*   k_ws  = (u16*)(p + 6291456);
    u16*   vt_ws = (u16*)(p + 12582912);
    u16*   po_ws = (u16*)(p + 18874368);
    u16*   xb    = (u16*)(p + 18874368);              // overlay
    u16*   wqb   = (u16*)(p + 25165824);
    u16*   wkb   = (u16*)(p + 26345472);
    u16*   wvb   = (u16*)(p + 27525120);
    float* l_ws  = (float*)(p + 34603008);
    u16*   wob   = (u16*)(p + 35094528);
    u16*   o_ws  = (u16*)(p + 36274176);

    convert_all<<<5376, 256, 0, stream>>>(x, Wq, Wk, Wv, Wo, xb, wqb, wkb, wvb, wob);
    gemm_qkv<<<dim3(32, 18), 256, 0, stream>>>(xb, wqb, wkb, wvb, bq, bk, bv, q_ws, k_ws, vt_ws);
    attn10<<<dim3(960), 256, 0, stream>>>(q_ws, k_ws, vt_ws, o_ws, po_ws, l_ws);
    combine_o<<<dim3(1152), 256, 0, stream>>>(po_ws, l_ws, o_ws);
    gemm_out64<<<dim3(64, 6), 256, 0, stream>>>(o_ws, wob, bo, out);
}

// Round 13
// 80.904 us; speedup vs baseline: 1.2404x; 1.0529x over previous
//
#include <hip/hip_runtime.h>

typedef unsigned short u16;
typedef unsigned int u32;
typedef unsigned long long u64;
typedef __attribute__((ext_vector_type(8))) short bfrag;    // 8 bf16 = 4 VGPRs
typedef __attribute__((ext_vector_type(4))) float f32x4;
typedef __attribute__((ext_vector_type(16))) float f32x16;
typedef __attribute__((ext_vector_type(4))) u32 u32x4;

#define QSCALE 0.18033688f   // 0.125 * log2(e): scores land in log2 domain

__device__ __forceinline__ u16 f2bf(float f) {
    unsigned u = __float_as_uint(f);
    u += 0x7FFFu + ((u >> 16) & 1u);           // RNE
    return (u16)(u >> 16);
}

__device__ __forceinline__ u32 cvt_pk_bf16(float lo, float hi) {
    u32 r;
    asm("v_cvt_pk_bf16_f32 %0, %1, %2" : "=v"(r) : "v"(lo), "v"(hi));
    return r;
}

// native 2^x (v_exp_f32); exp2f without fast-math lowers to guarded OCML libm.
__device__ __forceinline__ float fexp2(float x) {
    float r;
    asm("v_exp_f32 %0, %1" : "=v"(r) : "v"(x));
    return r;
}

__device__ __forceinline__ void glds16(const void* g, void* l) {
    __builtin_amdgcn_global_load_lds((__attribute__((address_space(1))) void*)g,
                                     (__attribute__((address_space(3))) void*)l,
                                     16, 0, 0);
}

__device__ __forceinline__ f32x16 mfma32(bfrag a, bfrag b, f32x16 c) {
    return __builtin_amdgcn_mfma_f32_32x32x16_bf16(a, b, c, 0, 0, 0);
}

#define WAIT_VM4()  asm volatile("s_waitcnt vmcnt(4)" ::: "memory")
#define WAIT_VM3()  asm volatile("s_waitcnt vmcnt(3)" ::: "memory")
#define WAIT_VM2()  asm volatile("s_waitcnt vmcnt(2)" ::: "memory")
#define WAIT_VM0()  asm volatile("s_waitcnt vmcnt(0)" ::: "memory")
#define BAR()       __builtin_amdgcn_s_barrier()
#define SCHED_FENCE() __builtin_amdgcn_sched_barrier(0)
#define PRIO(n)     __builtin_amdgcn_s_setprio(n)

// ---------------- convert: fp32 -> bf16 for x, Wq, Wk, Wv, Wo ----------------
__global__ __launch_bounds__(256) void convert_all(
    const float* __restrict__ x, const float* __restrict__ wq,
    const float* __restrict__ wk, const float* __restrict__ wv,
    const float* __restrict__ wo,
    u16* __restrict__ xb, u16* __restrict__ wqb, u16* __restrict__ wkb,
    u16* __restrict__ wvb, u16* __restrict__ wob) {
    const int XV = (2 * 2048 * 768) / 4;
    const int WV = (768 * 768) / 4;
    int i = blockIdx.x * 256 + threadIdx.x;
    if (i >= XV + 4 * WV) return;
    const float4* src; u16* dst; int off;
    if (i < XV) { src = (const float4*)x; dst = xb; off = i; }
    else {
        int j = i - XV; int z = j / WV; off = j - z * WV;
        src = (const float4*)(z == 0 ? wq : z == 1 ? wk : z == 2 ? wv : wo);
        dst = (z == 0 ? wqb : z == 1 ? wkb : z == 2 ? wvb : wob);
    }
    float4 v = src[off];
    u64 pk = (u64)f2bf(v.x)
        | ((u64)f2bf(v.y) << 16)
        | ((u64)f2bf(v.z) << 32)
        | ((u64)f2bf(v.w) << 48);
    *(u64*)(dst + off * 4) = pk;
}

// ---------------- GEMM core 128x128 ----------------
__device__ __forceinline__ void gemm_core(
    const u16* __restrict__ A, const u16* __restrict__ Bw, int m0,
    u16* a_lds, u16* b_lds, f32x4 acc[4][4]) {
    const int t = threadIdx.x;
    const int w = t >> 6, lane = t & 63, ln = lane & 15, lh = lane >> 4;
    const int wr = w >> 1, wc = w & 1;

    const int row0 = t >> 2;
    const int u0 = (t & 3) ^ ((row0 >> 1) & 3);
    const int row1 = row0 + 64;
    const int u1 = (t & 3) ^ ((row1 >> 1) & 3);
    const u16* ga0 = A + (m0 + row0) * 768 + u0 * 8;
    const u16* ga1 = A + (m0 + row1) * 768 + u1 * 8;
    const u16* gb0 = Bw + row0 * 768 + u0 * 8;
    const u16* gb1 = Bw + row1 * 768 + u1 * 8;
    u16* la = a_lds + w * 512;
    u16* lb = b_lds + w * 512;

    auto STAGE = [&](int k0, int bi) {
        glds16(ga0 + k0, la + bi * 4096);
        glds16(ga1 + k0, la + bi * 4096 + 2048);
        glds16(gb0 + k0, lb + bi * 4096);
        glds16(gb1 + k0, lb + bi * 4096 + 2048);
    };

    STAGE(0, 0);
    int cur = 0;
    for (int k0 = 0; k0 < 768; k0 += 32) {
        if (k0 + 32 < 768) {
            STAGE(k0 + 32, cur ^ 1);
            WAIT_VM4();
        } else {
            WAIT_VM0();
        }
        BAR();
        SCHED_FENCE();
        const u16* ab = a_lds + cur * 4096;
        const u16* bb = b_lds + cur * 4096;
        bfrag aF[4], bF[4];
#pragma unroll
        for (int i = 0; i < 4; i++) {
            int ra = wr * 64 + i * 16 + ln;
            aF[i] = *(const bfrag*)(ab + ra * 32 + ((lh ^ ((ra >> 1) & 3)) * 8));
            int rb = wc * 64 + i * 16 + ln;
            bF[i] = *(const bfrag*)(bb + rb * 32 + ((lh ^ ((rb >> 1) & 3)) * 8));
        }
#pragma unroll
        for (int i = 0; i < 4; i++)
#pragma unroll
            for (int j = 0; j < 4; j++)
                acc[i][j] = __builtin_amdgcn_mfma_f32_16x16x32_bf16(
                    aF[i], bF[j], acc[i][j], 0, 0, 0);
        SCHED_FENCE();
        BAR();
        cur ^= 1;
    }
}

// ---------------- QKV projection (128x128) ----------------
__global__ __launch_bounds__(256) void gemm_qkv(
    const u16* __restrict__ xb,
    const u16* __restrict__ wqb, const u16* __restrict__ wkb, const u16* __restrict__ wvb,
    const float* __restrict__ bq, const float* __restrict__ bk, const float* __restrict__ bv,
    u16* __restrict__ q_ws, u16* __restrict__ k_ws, u16* __restrict__ vt_ws) {
    __shared__ __align__(16) u16 smem[16384];         // a_lds 8192 | b_lds 8192
    u16* a_lds = smem;
    u16* b_lds = smem + 8192;
    const int m0 = blockIdx.x * 128;
    const int z = blockIdx.y / 6, nb = blockIdx.y % 6;
    const u16* Bw = (z == 0 ? wqb : z == 1 ? wkb : wvb) + nb * 128 * 768;
    const float* bias = (z == 0 ? bq : z == 1 ? bk : bv);

    f32x4 acc[4][4] = {};
    gemm_core(xb, Bw, m0, a_lds, b_lds, acc);

    const int t = threadIdx.x, w = t >> 6, lane = t & 63, ln = lane & 15, lh = lane >> 4;
    const int wr = w >> 1, wc = w & 1;
    if (z == 2) {
        // ---- LDS transpose: T[n=128][m=128] u16, 16B units swizzled by n ----
        __syncthreads();
        char* T = (char*)smem;
#pragma unroll
        for (int j = 0; j < 4; j++) {
            int nt = wc * 64 + j * 16 + ln;
            float bb = bias[nb * 128 + nt];
#pragma unroll
            for (int i = 0; i < 4; i++) {
                int m0t = wr * 64 + i * 16 + lh * 4;
                u64 pk = (u64)f2bf(acc[i][j][0] + bb)
                    | ((u64)f2bf(acc[i][j][1] + bb) << 16)
                    | ((u64)f2bf(acc[i][j][2] + bb) << 32)
                    | ((u64)f2bf(acc[i][j][3] + bb) << 48);
                int off = nt * 256 + ((m0t * 2) ^ ((nt & 15) << 4));
                *(u64*)(T + off) = pk;
            }
        }
        __syncthreads();
        const int b = m0 >> 11, s0 = m0 & 2047;
#pragma unroll
        for (int c = 0; c < 8; c++) {
            int g = c * 256 + t;
            int nt = g >> 4, mc = (g & 15) * 8;
            int off = nt * 256 + ((mc * 2) ^ ((nt & 15) << 4));
            u32x4 v = *(const u32x4*)(T + off);
            int nl = nb * 128 + nt;
            int h = nl >> 6, d = nl & 63;
            *(u32x4*)(vt_ws + ((size_t)((b * 12 + h) * 64 + d)) * 2048 + s0 + mc) = v;
        }
    } else {
        u16* dst = (z == 0 ? q_ws : k_ws);
        const float sc = (z == 0) ? QSCALE : 1.0f;
#pragma unroll
        for (int j = 0; j < 4; j++) {
            int nl = nb * 128 + wc * 64 + j * 16 + ln;
            int h = nl >> 6, d = nl & 63;
            float bb = bias[nl];
#pragma unroll
            for (int i = 0; i < 4; i++)
#pragma unroll
                for (int r = 0; r < 4; r++) {
                    int m = m0 + wr * 64 + i * 16 + lh * 4 + r;
                    int b = m >> 11, s = m & 2047;
                    dst[((size_t)((b * 12 + h) * 2048 + s)) * 64 + d] = f2bf((acc[i][j][r] + bb) * sc);
                }
        }
    }
}

// ---------------- GEMM core 64x128 (for output projection) ----------------
__device__ __forceinline__ void gemm_core64(
    const u16* __restrict__ A, const u16* __restrict__ Bw, int m0,
    u16* a_lds, u16* b_lds, f32x4 acc[2][4]) {
    const int t = threadIdx.x;
    const int w = t >> 6, lane = t & 63, ln = lane & 15, lh = lane >> 4;
    const int wr = w >> 1, wc = w & 1;

    const int rowA = t >> 2;
    const int uA = (t & 3) ^ ((rowA >> 1) & 3);
    const int rowB1 = rowA + 64;
    const int uB1 = (t & 3) ^ ((rowB1 >> 1) & 3);
    const u16* ga  = A + (m0 + rowA) * 768 + uA * 8;
    const u16* gb0 = Bw + rowA * 768 + uA * 8;
    const u16* gb1 = Bw + rowB1 * 768 + uB1 * 8;
    u16* la = a_lds + w * 512;
    u16* lb = b_lds + w * 512;

    auto STAGE = [&](int k0, int bi) {
        glds16(ga + k0, la + bi * 2048);
        glds16(gb0 + k0, lb + bi * 4096);
        glds16(gb1 + k0, lb + bi * 4096 + 2048);
    };

    STAGE(0, 0);
    int cur = 0;
    for (int k0 = 0; k0 < 768; k0 += 32) {
        if (k0 + 32 < 768) {
            STAGE(k0 + 32, cur ^ 1);
            WAIT_VM3();
        } else {
            WAIT_VM0();
        }
        BAR();
        SCHED_FENCE();
        const u16* ab = a_lds + cur * 2048;
        const u16* bb = b_lds + cur * 4096;
        bfrag aF[2], bF[4];
#pragma unroll
        for (int i = 0; i < 2; i++) {
            int ra = wr * 32 + i * 16 + ln;
            aF[i] = *(const bfrag*)(ab + ra * 32 + ((lh ^ ((ra >> 1) & 3)) * 8));
        }
#pragma unroll
        for (int j = 0; j < 4; j++) {
            int rb = wc * 64 + j * 16 + ln;
            bF[j] = *(const bfrag*)(bb + rb * 32 + ((lh ^ ((rb >> 1) & 3)) * 8));
        }
#pragma unroll
        for (int i = 0; i < 2; i++)
#pragma unroll
            for (int j = 0; j < 4; j++)
                acc[i][j] = __builtin_amdgcn_mfma_f32_16x16x32_bf16(
                    aF[i], bF[j], acc[i][j], 0, 0, 0);
        SCHED_FENCE();
        BAR();
        cur ^= 1;
    }
}

// ---------------- output projection: 64x128 tiles, 384 blocks ----------------
__global__ __launch_bounds__(256) void gemm_out64(
    const u16* __restrict__ ob, const u16* __restrict__ wob,
    const float* __restrict__ bo, float* __restrict__ out) {
    __shared__ __align__(16) u16 a_lds[2 * 64 * 32];
    __shared__ __align__(16) u16 b_lds[2 * 128 * 32];
    const int m0 = blockIdx.x * 64, n0 = blockIdx.y * 128;
    f32x4 acc[2][4] = {};
    gemm_core64(ob, wob + n0 * 768, m0, a_lds, b_lds, acc);
    const int t = threadIdx.x, w = t >> 6, lane = t & 63, ln = lane & 15, lh = lane >> 4;
    const int wr = w >> 1, wc = w & 1;
#pragma unroll
    for (int j = 0; j < 4; j++) {
        int n = n0 + wc * 64 + j * 16 + ln;
        float bb = bo[n];
#pragma unroll
        for (int i = 0; i < 2; i++)
#pragma unroll
            for (int r = 0; r < 4; r++) {
                int m = m0 + wr * 32 + i * 16 + lh * 4 + r;
                out[m * 768 + n] = acc[i][j][r] + bb;
            }
    }
}

// ---------------- attention v12: 8-wave blocks, one staging serves 8 q-tiles -------
// 480 blocks = 24 bh x 20 (t7, piece). Wave w = tile ti=w (all 8 tiles of the t7
// group). Staging per iter: 2 glds16/wave (K 8KB + V 8KB across 8 waves), halved
// L2 traffic vs 4-wave quads. Same per-wave math as v10 (native v_exp softmax).
__global__ __launch_bounds__(512) void attn12(
    const u16* __restrict__ q_ws, const u16* __restrict__ k_ws,
    const u16* __restrict__ vt_ws, u16* __restrict__ o_ws,
    u16* __restrict__ po_ws, float* __restrict__ l_ws) {
    __shared__ __align__(16) u16 k_lds[2][64 * 64];   // [key][d], 16B units u^=key&7
    __shared__ __align__(16) u16 v_lds[2][64 * 64];   // [d][key], 16B units u^=d&7

    const int t = threadIdx.x, w = t >> 6, l = t & 63, lq = l & 31, H = l >> 5;
    int id = blockIdx.x;
    int bh8 = id & 7, idq = id >> 3;                  // XCD pin on bh%8
    int bhq = idq % 3, pg = idq / 3;                  // pg 0..19, heavy t7 first
    int t7, piece;
    if (pg < 4)       { t7 = 7; piece = pg; }
    else if (pg < 8)  { t7 = 6; piece = pg - 4; }
    else if (pg < 11) { t7 = 5; piece = pg - 8; }
    else if (pg < 14) { t7 = 4; piece = pg - 11; }
    else if (pg < 16) { t7 = 3; piece = pg - 14; }
    else if (pg < 18) { t7 = 2; piece = pg - 16; }
    else if (pg == 18){ t7 = 1; piece = 0; }
    else              { t7 = 0; piece = 0; }
    const int np = (t7 + 2) >> 1;                     // pieces per tile (8 iters each)
    const int bh = bhq * 8 + bh8;
    const int ti = w;                                 // 0..7: one tile per wave
    const int tile = t7 + 8 * ti;
    const int qw0 = tile * 32;

    const u16* Qb = q_ws + (size_t)bh * 2048 * 64;
    const u16* Kb = k_ws + (size_t)bh * 2048 * 64;
    const u16* Vt = vt_ws + (size_t)bh * 64 * 2048;

    // permuted K-row index (swap bits 2<->3 of lq)
    const int lqp = (lq & 19) | ((lq & 4) << 1) | ((lq & 8) >> 1);
    const int ksw = lqp & 7;
    const int vsw = lq & 7;

    bfrag qF[4];
#pragma unroll
    for (int kd = 0; kd < 4; kd++)
        qF[kd] = *(const bfrag*)(Qb + (size_t)(qw0 + lq) * 64 + kd * 16 + H * 8);

    const f32x16 Z = {};
    f32x16 O0 = Z, O1 = Z;
    float lsum = 0.f;

    // staging: 512 threads cover 64 rows x 8 units each for K and V
    const int skey = t >> 3;                          // 0..63
    const int su = (t & 7) ^ (skey & 7);

    auto STAGE = [&](int k0, int bi) {
        glds16(Kb + (size_t)(k0 + skey) * 64 + su * 8, k_lds[bi] + w * 512);
        glds16(Vt + (size_t)skey * 2048 + k0 + su * 8, v_lds[bi] + w * 512);
    };

    int gp0 = piece * 8;
    int win = gp0 / np, pb = gp0 - win * np;
    STAGE(win * 256 + pb * 64, 0);

    for (int j = 0; j < 8; ++j) {
        int winn = win, pbn = pb + 1;
        if (pbn == np) { pbn = 0; winn = win + 1; }
        if (j < 7) {
            STAGE(winn * 256 + pbn * 64, (j + 1) & 1);
            WAIT_VM2();                               // current's 2 landed; next 2 in flight
        } else {
            WAIT_VM0();
        }
        BAR();
        SCHED_FENCE();

        const int cb = 2 * pb;
        const bool c1 = (cb + 1) <= t7, d0 = (cb == t7), d1 = (cb + 1 == t7);
        const u16* kl = k_lds[j & 1];
        const u16* vl = v_lds[j & 1];

        // S^T = K . Q with permuted key rows
        PRIO(1);
        f32x16 s0, s1;
        {
            bfrag kf = *(const bfrag*)(kl + lqp * 64 + ((H) ^ ksw) * 8);
            s0 = mfma32(kf, qF[0], Z);
#pragma unroll
            for (int kd = 1; kd < 4; kd++) {
                bfrag k2 = *(const bfrag*)(kl + lqp * 64 + ((kd * 2 + H) ^ ksw) * 8);
                s0 = mfma32(k2, qF[kd], s0);
            }
        }
        if (c1) {
            bfrag kf = *(const bfrag*)(kl + (32 + lqp) * 64 + ((H) ^ ksw) * 8);
            s1 = mfma32(kf, qF[0], Z);
#pragma unroll
            for (int kd = 1; kd < 4; kd++) {
                bfrag k2 = *(const bfrag*)(kl + (32 + lqp) * 64 + ((kd * 2 + H) ^ ksw) * 8);
                s1 = mfma32(k2, qF[kd], s1);
            }
        }
        PRIO(0);

        // fixed-scale softmax: p = 2^s via native v_exp; diagonal masked
        float ps = 0.f;
        u32 pkA[8], pkB[8];
        if (d0) {
#pragma unroll
            for (int r2 = 0; r2 < 16; r2++) {
                int ka = (r2 & 3) + 4 * ((r2 >> 2) & 1) + 16 * (r2 >> 3) + 8 * H;
                if (ka > lq) s0[r2] = -1e30f;
            }
        }
#pragma unroll
        for (int i = 0; i < 8; i++) {
            float a = fexp2(s0[2 * i]), b2 = fexp2(s0[2 * i + 1]);
            ps += a + b2; pkA[i] = cvt_pk_bf16(a, b2);
        }
        if (c1) {
            if (d1) {
#pragma unroll
                for (int r2 = 0; r2 < 16; r2++) {
                    int ka = (r2 & 3) + 4 * ((r2 >> 2) & 1) + 16 * (r2 >> 3) + 8 * H;
                    if (ka > lq) s1[r2] = -1e30f;
                }
            }
#pragma unroll
            for (int i = 0; i < 8; i++) {
                float a = fexp2(s1[2 * i]), b2 = fexp2(s1[2 * i + 1]);
                ps += a + b2; pkB[i] = cvt_pk_bf16(a, b2);
            }
        }
        lsum += ps;                                   // cross-half reduce deferred

        // PV: A-frags direct from pk words (zero shuffle); B = contiguous V runs
        PRIO(1);
        {
            u32x4 a0 = {pkA[0], pkA[1], pkA[2], pkA[3]};
            u32x4 a1 = {pkA[4], pkA[5], pkA[6], pkA[7]};
            bfrag A0 = __builtin_bit_cast(bfrag, a0);
            bfrag A1 = __builtin_bit_cast(bfrag, a1);
            bfrag v00 = *(const bfrag*)(vl + lq * 64 + ((H) ^ vsw) * 8);
            bfrag v01 = *(const bfrag*)(vl + (32 + lq) * 64 + ((H) ^ vsw) * 8);
            bfrag v10 = *(const bfrag*)(vl + lq * 64 + ((2 + H) ^ vsw) * 8);
            bfrag v11 = *(const bfrag*)(vl + (32 + lq) * 64 + ((2 + H) ^ vsw) * 8);
            O0 = mfma32(A0, v00, O0);
            O1 = mfma32(A0, v01, O1);
            O0 = mfma32(A1, v10, O0);
            O1 = mfma32(A1, v11, O1);
        }
        if (c1) {
            u32x4 a0 = {pkB[0], pkB[1], pkB[2], pkB[3]};
            u32x4 a1 = {pkB[4], pkB[5], pkB[6], pkB[7]};
            bfrag A0 = __builtin_bit_cast(bfrag, a0);
            bfrag A1 = __builtin_bit_cast(bfrag, a1);
            bfrag v00 = *(const bfrag*)(vl + lq * 64 + ((4 + H) ^ vsw) * 8);
            bfrag v01 = *(const bfrag*)(vl + (32 + lq) * 64 + ((4 + H) ^ vsw) * 8);
            bfrag v10 = *(const bfrag*)(vl + lq * 64 + ((6 + H) ^ vsw) * 8);
            bfrag v11 = *(const bfrag*)(vl + (32 + lq) * 64 + ((6 + H) ^ vsw) * 8);
            O0 = mfma32(A0, v00, O0);
            O1 = mfma32(A0, v01, O1);
            O0 = mfma32(A1, v10, O0);
            O1 = mfma32(A1, v11, O1);
        }
        PRIO(0);
        SCHED_FENCE();
        BAR();
        win = winn; pb = pbn;
    }

    float lsT = lsum + __shfl_xor(lsum, 32);
    if (np == 1) {
        // single piece == full tile: normalize and write o directly
        float linv = 1.f / lsT;
        const int b = bh / 12, h = bh % 12;
#pragma unroll
        for (int r2 = 0; r2 < 16; r2++) {
            int row = (r2 & 3) + 8 * (r2 >> 2) + 4 * H;
            float fr = __shfl(linv, row);
            size_t base = ((size_t)(b * 2048 + qw0 + row)) * 768 + h * 64;
            o_ws[base + lq] = f2bf(O0[r2] * fr);
            o_ws[base + 32 + lq] = f2bf(O1[r2] * fr);
        }
    } else {
        // partial store: po[q][d] bf16 + l (combine normalizes)
        const int cum8[8] = {0, 8, 16, 32, 48, 72, 96, 128};
        size_t pidx = (size_t)bh * 160 + cum8[t7] + ti * np + piece;
        u16* po = po_ws + pidx * 2048;
#pragma unroll
        for (int r2 = 0; r2 < 16; r2++) {
            int row = (r2 & 3) + 8 * (r2 >> 2) + 4 * H;   // query row (unpermuted)
            po[row * 64 + lq] = f2bf(O0[r2]);
            po[row * 64 + 32 + lq] = f2bf(O1[r2]);
        }
        if (l < 32) l_ws[pidx * 32 + lq] = lsT;
    }
}

// ---------------- combine partial O pieces (t7 >= 2 tiles only) ----------------
__global__ __launch_bounds__(256) void combine_o(
    const u16* __restrict__ po_ws, const float* __restrict__ l_ws,
    u16* __restrict__ o_ws) {
    int id = blockIdx.x;                              // 1152 = 24 bh x 48 tiles (t7>=2)
    int bh8 = id & 7, idq = id >> 3;
    int bhq = idq % 3, r = idq / 3;
    int bh = bhq * 8 + bh8;
    int t7 = 2 + (r >> 3), ti = r & 7;
    int tile = t7 + 8 * ti;
    int np = (t7 + 2) >> 1;
    const int cum8[8] = {0, 8, 16, 32, 48, 72, 96, 128};
    size_t base = (size_t)bh * 160 + cum8[t7] + ti * np;
    int t = threadIdx.x;
    int q = t >> 3, d8 = (t & 7) * 8;
    float acc[8] = {0.f, 0.f, 0.f, 0.f, 0.f, 0.f, 0.f, 0.f};
    float lt = 0.f;
    for (int i = 0; i < np; i++) {
        lt += l_ws[(base + i) * 32 + q];
        bfrag v = *(const bfrag*)(po_ws + (base + i) * 2048 + q * 64 + d8);
#pragma unroll
        for (int e = 0; e < 8; e++)
            acc[e] += __uint_as_float(((u32)(u16)v[e]) << 16);
    }
    float inv = 1.f / lt;
    u32x4 pkv;
#pragma unroll
    for (int e = 0; e < 4; e++)
        pkv[e] = cvt_pk_bf16(acc[2 * e] * inv, acc[2 * e + 1] * inv);
    int b = bh / 12, h = bh % 12;
    size_t dst = ((size_t)(b * 2048 + tile * 32 + q)) * 768 + h * 64 + d8;
    *(u32x4*)(o_ws + dst) = pkv;
}

// ---------------- launcher ----------------
extern "C" void kernel_launch(void* const* d_in, const int* in_sizes, int n_in,
                              void* d_out, int out_size, void* d_ws, size_t ws_size,
                              hipStream_t stream) {
    const float* x  = (const float*)d_in[0];
    const float* Wq = (const float*)d_in[1];
    const float* bq = (const float*)d_in[2];
    const float* Wk = (const float*)d_in[3];
    const float* bk = (const float*)d_in[4];
    const float* Wv = (const float*)d_in[5];
    const float* bv = (const float*)d_in[6];
    const float* Wo = (const float*)d_in[7];
    const float* bo = (const float*)d_in[8];
    float* out = (float*)d_out;

    char* p = (char*)d_ws;
    u16*   q_ws  = (u16*)(p + 0);
    u16*   k_ws  = (u16*)(p + 6291456);
    u16*   vt_ws = (u16*)(p + 12582912);
    u16*   po_ws = (u16*)(p + 18874368);
    u16*   xb    = (u16*)(p + 18874368);              // overlay
    u16*   wqb   = (u16*)(p + 25165824);
    u16*   wkb   = (u16*)(p + 26345472);
    u16*   wvb   = (u16*)(p + 27525120);
    float* l_ws  = (float*)(p + 34603008);
    u16*   wob   = (u16*)(p + 35094528);
    u16*   o_ws  = (u16*)(p + 36274176);

    convert_all<<<5376, 256, 0, stream>>>(x, Wq, Wk, Wv, Wo, xb, wqb, wkb, wvb, wob);
    gemm_qkv<<<dim3(32, 18), 256, 0, stream>>>(xb, wqb, wkb, wvb, bq, bk, bv, q_ws, k_ws, vt_ws);
    attn12<<<dim3(480), 512, 0, stream>>>(q_ws, k_ws, vt_ws, o_ws, po_ws, l_ws);
    combine_o<<<dim3(1152), 256, 0, stream>>>(po_ws, l_ws, o_ws);
    gemm_out64<<<dim3(64, 6), 256, 0, stream>>>(o_ws, wob, bo, out);
}

// Round 14
// 79.238 us; speedup vs baseline: 1.2665x; 1.0210x over previous
//
#include <hip/hip_runtime.h>

typedef unsigned short u16;
typedef unsigned int u32;
typedef unsigned long long u64;
typedef __attribute__((ext_vector_type(8))) short bfrag;    // 8 bf16 = 4 VGPRs
typedef __attribute__((ext_vector_type(4))) float f32x4;
typedef __attribute__((ext_vector_type(16))) float f32x16;
typedef __attribute__((ext_vector_type(4))) u32 u32x4;

#define QSCALE 0.18033688f   // 0.125 * log2(e): scores land in log2 domain

__device__ __forceinline__ u16 f2bf(float f) {
    unsigned u = __float_as_uint(f);
    u += 0x7FFFu + ((u >> 16) & 1u);           // RNE
    return (u16)(u >> 16);
}

__device__ __forceinline__ u32 cvt_pk_bf16(float lo, float hi) {
    u32 r;
    asm("v_cvt_pk_bf16_f32 %0, %1, %2" : "=v"(r) : "v"(lo), "v"(hi));
    return r;
}

// native 2^x (v_exp_f32); exp2f without fast-math lowers to guarded OCML libm.
__device__ __forceinline__ float fexp2(float x) {
    float r;
    asm("v_exp_f32 %0, %1" : "=v"(r) : "v"(x));
    return r;
}

__device__ __forceinline__ void glds16(const void* g, void* l) {
    __builtin_amdgcn_global_load_lds((__attribute__((address_space(1))) void*)g,
                                     (__attribute__((address_space(3))) void*)l,
                                     16, 0, 0);
}

__device__ __forceinline__ f32x16 mfma32(bfrag a, bfrag b, f32x16 c) {
    return __builtin_amdgcn_mfma_f32_32x32x16_bf16(a, b, c, 0, 0, 0);
}

#define WAIT_VM4()  asm volatile("s_waitcnt vmcnt(4)" ::: "memory")
#define WAIT_VM3()  asm volatile("s_waitcnt vmcnt(3)" ::: "memory")
#define WAIT_VM2()  asm volatile("s_waitcnt vmcnt(2)" ::: "memory")
#define WAIT_VM0()  asm volatile("s_waitcnt vmcnt(0)" ::: "memory")
#define BAR()       __builtin_amdgcn_s_barrier()
#define SCHED_FENCE() __builtin_amdgcn_sched_barrier(0)
#define PRIO(n)     __builtin_amdgcn_s_setprio(n)

// ---------------- convert: fp32 -> bf16 for x, Wq, Wk, Wv, Wo ----------------
__global__ __launch_bounds__(256) void convert_all(
    const float* __restrict__ x, const float* __restrict__ wq,
    const float* __restrict__ wk, const float* __restrict__ wv,
    const float* __restrict__ wo,
    u16* __restrict__ xb, u16* __restrict__ wqb, u16* __restrict__ wkb,
    u16* __restrict__ wvb, u16* __restrict__ wob) {
    const int XV = (2 * 2048 * 768) / 4;
    const int WV = (768 * 768) / 4;
    int i = blockIdx.x * 256 + threadIdx.x;
    if (i >= XV + 4 * WV) return;
    const float4* src; u16* dst; int off;
    if (i < XV) { src = (const float4*)x; dst = xb; off = i; }
    else {
        int j = i - XV; int z = j / WV; off = j - z * WV;
        src = (const float4*)(z == 0 ? wq : z == 1 ? wk : z == 2 ? wv : wo);
        dst = (z == 0 ? wqb : z == 1 ? wkb : z == 2 ? wvb : wob);
    }
    float4 v = src[off];
    u64 pk = (u64)f2bf(v.x)
        | ((u64)f2bf(v.y) << 16)
        | ((u64)f2bf(v.z) << 32)
        | ((u64)f2bf(v.w) << 48);
    *(u64*)(dst + off * 4) = pk;
}

// ---------------- GEMM core 128x128 (2-buffer; 3-buf would cost occupancy) ----------
__device__ __forceinline__ void gemm_core(
    const u16* __restrict__ A, const u16* __restrict__ Bw, int m0,
    u16* a_lds, u16* b_lds, f32x4 acc[4][4]) {
    const int t = threadIdx.x;
    const int w = t >> 6, lane = t & 63, ln = lane & 15, lh = lane >> 4;
    const int wr = w >> 1, wc = w & 1;

    const int row0 = t >> 2;
    const int u0 = (t & 3) ^ ((row0 >> 1) & 3);
    const int row1 = row0 + 64;
    const int u1 = (t & 3) ^ ((row1 >> 1) & 3);
    const u16* ga0 = A + (m0 + row0) * 768 + u0 * 8;
    const u16* ga1 = A + (m0 + row1) * 768 + u1 * 8;
    const u16* gb0 = Bw + row0 * 768 + u0 * 8;
    const u16* gb1 = Bw + row1 * 768 + u1 * 8;
    u16* la = a_lds + w * 512;
    u16* lb = b_lds + w * 512;

    auto STAGE = [&](int k0, int bi) {
        glds16(ga0 + k0, la + bi * 4096);
        glds16(ga1 + k0, la + bi * 4096 + 2048);
        glds16(gb0 + k0, lb + bi * 4096);
        glds16(gb1 + k0, lb + bi * 4096 + 2048);
    };

    STAGE(0, 0);
    int cur = 0;
    for (int k0 = 0; k0 < 768; k0 += 32) {
        if (k0 + 32 < 768) {
            STAGE(k0 + 32, cur ^ 1);
            WAIT_VM4();
        } else {
            WAIT_VM0();
        }
        BAR();
        SCHED_FENCE();
        const u16* ab = a_lds + cur * 4096;
        const u16* bb = b_lds + cur * 4096;
        bfrag aF[4], bF[4];
#pragma unroll
        for (int i = 0; i < 4; i++) {
            int ra = wr * 64 + i * 16 + ln;
            aF[i] = *(const bfrag*)(ab + ra * 32 + ((lh ^ ((ra >> 1) & 3)) * 8));
            int rb = wc * 64 + i * 16 + ln;
            bF[i] = *(const bfrag*)(bb + rb * 32 + ((lh ^ ((rb >> 1) & 3)) * 8));
        }
#pragma unroll
        for (int i = 0; i < 4; i++)
#pragma unroll
            for (int j = 0; j < 4; j++)
                acc[i][j] = __builtin_amdgcn_mfma_f32_16x16x32_bf16(
                    aF[i], bF[j], acc[i][j], 0, 0, 0);
        SCHED_FENCE();
        BAR();
        cur ^= 1;
    }
}

// ---------------- QKV projection (128x128) ----------------
__global__ __launch_bounds__(256) void gemm_qkv(
    const u16* __restrict__ xb,
    const u16* __restrict__ wqb, const u16* __restrict__ wkb, const u16* __restrict__ wvb,
    const float* __restrict__ bq, const float* __restrict__ bk, const float* __restrict__ bv,
    u16* __restrict__ q_ws, u16* __restrict__ k_ws, u16* __restrict__ vt_ws) {
    __shared__ __align__(16) u16 smem[16384];         // a_lds 8192 | b_lds 8192
    u16* a_lds = smem;
    u16* b_lds = smem + 8192;
    const int m0 = blockIdx.x * 128;
    const int z = blockIdx.y / 6, nb = blockIdx.y % 6;
    const u16* Bw = (z == 0 ? wqb : z == 1 ? wkb : wvb) + nb * 128 * 768;
    const float* bias = (z == 0 ? bq : z == 1 ? bk : bv);

    f32x4 acc[4][4] = {};
    gemm_core(xb, Bw, m0, a_lds, b_lds, acc);

    const int t = threadIdx.x, w = t >> 6, lane = t & 63, ln = lane & 15, lh = lane >> 4;
    const int wr = w >> 1, wc = w & 1;
    if (z == 2) {
        // ---- LDS transpose: T[n=128][m=128] u16, 16B units swizzled by n ----
        __syncthreads();
        char* T = (char*)smem;
#pragma unroll
        for (int j = 0; j < 4; j++) {
            int nt = wc * 64 + j * 16 + ln;
            float bb = bias[nb * 128 + nt];
#pragma unroll
            for (int i = 0; i < 4; i++) {
                int m0t = wr * 64 + i * 16 + lh * 4;
                u64 pk = (u64)f2bf(acc[i][j][0] + bb)
                    | ((u64)f2bf(acc[i][j][1] + bb) << 16)
                    | ((u64)f2bf(acc[i][j][2] + bb) << 32)
                    | ((u64)f2bf(acc[i][j][3] + bb) << 48);
                int off = nt * 256 + ((m0t * 2) ^ ((nt & 15) << 4));
                *(u64*)(T + off) = pk;
            }
        }
        __syncthreads();
        const int b = m0 >> 11, s0 = m0 & 2047;
#pragma unroll
        for (int c = 0; c < 8; c++) {
            int g = c * 256 + t;
            int nt = g >> 4, mc = (g & 15) * 8;
            int off = nt * 256 + ((mc * 2) ^ ((nt & 15) << 4));
            u32x4 v = *(const u32x4*)(T + off);
            int nl = nb * 128 + nt;
            int h = nl >> 6, d = nl & 63;
            *(u32x4*)(vt_ws + ((size_t)((b * 12 + h) * 64 + d)) * 2048 + s0 + mc) = v;
        }
    } else {
        u16* dst = (z == 0 ? q_ws : k_ws);
        const float sc = (z == 0) ? QSCALE : 1.0f;
#pragma unroll
        for (int j = 0; j < 4; j++) {
            int nl = nb * 128 + wc * 64 + j * 16 + ln;
            int h = nl >> 6, d = nl & 63;
            float bb = bias[nl];
#pragma unroll
            for (int i = 0; i < 4; i++)
#pragma unroll
                for (int r = 0; r < 4; r++) {
                    int m = m0 + wr * 64 + i * 16 + lh * 4 + r;
                    int b = m >> 11, s = m & 2047;
                    dst[((size_t)((b * 12 + h) * 2048 + s)) * 64 + d] = f2bf((acc[i][j][r] + bb) * sc);
                }
        }
    }
}

// ---------------- GEMM core 64x128, 3-buffer, single barrier per K-step ----------
__device__ __forceinline__ void gemm_core64(
    const u16* __restrict__ A, const u16* __restrict__ Bw, int m0,
    u16* a_lds, u16* b_lds, f32x4 acc[2][4]) {
    const int t = threadIdx.x;
    const int w = t >> 6, lane = t & 63, ln = lane & 15, lh = lane >> 4;
    const int wr = w >> 1, wc = w & 1;

    const int rowA = t >> 2;
    const int uA = (t & 3) ^ ((rowA >> 1) & 3);
    const int rowB1 = rowA + 64;
    const int uB1 = (t & 3) ^ ((rowB1 >> 1) & 3);
    const u16* ga  = A + (m0 + rowA) * 768 + uA * 8;
    const u16* gb0 = Bw + rowA * 768 + uA * 8;
    const u16* gb1 = Bw + rowB1 * 768 + uB1 * 8;
    u16* la = a_lds + w * 512;
    u16* lb = b_lds + w * 512;

    auto STAGE = [&](int k0, int bi) {
        glds16(ga + k0, la + bi * 2048);
        glds16(gb0 + k0, lb + bi * 4096);
        glds16(gb1 + k0, lb + bi * 4096 + 2048);
    };

    STAGE(0, 0);
    int cur = 0, nxt = 1;
    for (int k0 = 0; k0 < 768; k0 += 32) {
        if (k0 + 32 < 768) {
            STAGE(k0 + 32, nxt);
            WAIT_VM3();
        } else {
            WAIT_VM0();
        }
        BAR();                                 // single barrier: 3-buf makes WAR safe
        SCHED_FENCE();
        const u16* ab = a_lds + cur * 2048;
        const u16* bb = b_lds + cur * 4096;
        bfrag aF[2], bF[4];
#pragma unroll
        for (int i = 0; i < 2; i++) {
            int ra = wr * 32 + i * 16 + ln;
            aF[i] = *(const bfrag*)(ab + ra * 32 + ((lh ^ ((ra >> 1) & 3)) * 8));
        }
#pragma unroll
        for (int j = 0; j < 4; j++) {
            int rb = wc * 64 + j * 16 + ln;
            bF[j] = *(const bfrag*)(bb + rb * 32 + ((lh ^ ((rb >> 1) & 3)) * 8));
        }
#pragma unroll
        for (int i = 0; i < 2; i++)
#pragma unroll
            for (int j = 0; j < 4; j++)
                acc[i][j] = __builtin_amdgcn_mfma_f32_16x16x32_bf16(
                    aF[i], bF[j], acc[i][j], 0, 0, 0);
        cur = nxt;
        nxt = (nxt == 2) ? 0 : nxt + 1;
    }
}

// ---------------- output projection: 64x128 tiles, 384 blocks, 3-buf ----------------
__global__ __launch_bounds__(256) void gemm_out64(
    const u16* __restrict__ ob, const u16* __restrict__ wob,
    const float* __restrict__ bo, float* __restrict__ out) {
    __shared__ __align__(16) u16 a_lds[3 * 64 * 32];    // 3 x 2048 u16
    __shared__ __align__(16) u16 b_lds[3 * 128 * 32];   // 3 x 4096 u16
    const int m0 = blockIdx.x * 64, n0 = blockIdx.y * 128;
    f32x4 acc[2][4] = {};
    gemm_core64(ob, wob + n0 * 768, m0, a_lds, b_lds, acc);
    const int t = threadIdx.x, w = t >> 6, lane = t & 63, ln = lane & 15, lh = lane >> 4;
    const int wr = w >> 1, wc = w & 1;
#pragma unroll
    for (int j = 0; j < 4; j++) {
        int n = n0 + wc * 64 + j * 16 + ln;
        float bb = bo[n];
#pragma unroll
        for (int i = 0; i < 2; i++)
#pragma unroll
            for (int r = 0; r < 4; r++) {
                int m = m0 + wr * 32 + i * 16 + lh * 4 + r;
                out[m * 768 + n] = acc[i][j][r] + bb;
            }
    }
}

// ---------------- attention v13: 8-wave blocks, 3-buffer, single barrier/iter -------
__global__ __launch_bounds__(512) void attn13(
    const u16* __restrict__ q_ws, const u16* __restrict__ k_ws,
    const u16* __restrict__ vt_ws, u16* __restrict__ o_ws,
    u16* __restrict__ po_ws, float* __restrict__ l_ws) {
    __shared__ __align__(16) u16 k_lds[3][64 * 64];   // [key][d], 16B units u^=key&7
    __shared__ __align__(16) u16 v_lds[3][64 * 64];   // [d][key], 16B units u^=d&7

    const int t = threadIdx.x, w = t >> 6, l = t & 63, lq = l & 31, H = l >> 5;
    int id = blockIdx.x;
    int bh8 = id & 7, idq = id >> 3;                  // XCD pin on bh%8
    int bhq = idq % 3, pg = idq / 3;                  // pg 0..19, heavy t7 first
    int t7, piece;
    if (pg < 4)       { t7 = 7; piece = pg; }
    else if (pg < 8)  { t7 = 6; piece = pg - 4; }
    else if (pg < 11) { t7 = 5; piece = pg - 8; }
    else if (pg < 14) { t7 = 4; piece = pg - 11; }
    else if (pg < 16) { t7 = 3; piece = pg - 14; }
    else if (pg < 18) { t7 = 2; piece = pg - 16; }
    else if (pg == 18){ t7 = 1; piece = 0; }
    else              { t7 = 0; piece = 0; }
    const int np = (t7 + 2) >> 1;                     // pieces per tile (8 iters each)
    const int bh = bhq * 8 + bh8;
    const int ti = w;                                 // 0..7: one tile per wave
    const int tile = t7 + 8 * ti;
    const int qw0 = tile * 32;

    const u16* Qb = q_ws + (size_t)bh * 2048 * 64;
    const u16* Kb = k_ws + (size_t)bh * 2048 * 64;
    const u16* Vt = vt_ws + (size_t)bh * 64 * 2048;

    // permuted K-row index (swap bits 2<->3 of lq)
    const int lqp = (lq & 19) | ((lq & 4) << 1) | ((lq & 8) >> 1);
    const int ksw = lqp & 7;
    const int vsw = lq & 7;

    bfrag qF[4];
#pragma unroll
    for (int kd = 0; kd < 4; kd++)
        qF[kd] = *(const bfrag*)(Qb + (size_t)(qw0 + lq) * 64 + kd * 16 + H * 8);

    const f32x16 Z = {};
    f32x16 O0 = Z, O1 = Z;
    float lsum = 0.f;

    // staging: 512 threads cover 64 rows x 8 units each for K and V
    const int skey = t >> 3;                          // 0..63
    const int su = (t & 7) ^ (skey & 7);

    auto STAGE = [&](int k0, int bi) {
        glds16(Kb + (size_t)(k0 + skey) * 64 + su * 8, (u16*)k_lds + bi * 4096 + w * 512);
        glds16(Vt + (size_t)skey * 2048 + k0 + su * 8, (u16*)v_lds + bi * 4096 + w * 512);
    };

    int gp0 = piece * 8;
    int win = gp0 / np, pb = gp0 - win * np;
    STAGE(win * 256 + pb * 64, 0);

    int cur = 0, nxt = 1;
    for (int j = 0; j < 8; ++j) {
        int winn = win, pbn = pb + 1;
        if (pbn == np) { pbn = 0; winn = win + 1; }
        if (j < 7) {
            STAGE(winn * 256 + pbn * 64, nxt);
            WAIT_VM2();                               // current's 2 landed; next 2 in flight
        } else {
            WAIT_VM0();
        }
        BAR();                                        // single barrier: 3-buf makes WAR safe
        SCHED_FENCE();

        const int cb = 2 * pb;
        const bool c1 = (cb + 1) <= t7, d0 = (cb == t7), d1 = (cb + 1 == t7);
        const u16* kl = (const u16*)k_lds + cur * 4096;
        const u16* vl = (const u16*)v_lds + cur * 4096;

        // S^T = K . Q with permuted key rows
        PRIO(1);
        f32x16 s0, s1;
        {
            bfrag kf = *(const bfrag*)(kl + lqp * 64 + ((H) ^ ksw) * 8);
            s0 = mfma32(kf, qF[0], Z);
#pragma unroll
            for (int kd = 1; kd < 4; kd++) {
                bfrag k2 = *(const bfrag*)(kl + lqp * 64 + ((kd * 2 + H) ^ ksw) * 8);
                s0 = mfma32(k2, qF[kd], s0);
            }
        }
        if (c1) {
            bfrag kf = *(const bfrag*)(kl + (32 + lqp) * 64 + ((H) ^ ksw) * 8);
            s1 = mfma32(kf, qF[0], Z);
#pragma unroll
            for (int kd = 1; kd < 4; kd++) {
                bfrag k2 = *(const bfrag*)(kl + (32 + lqp) * 64 + ((kd * 2 + H) ^ ksw) * 8);
                s1 = mfma32(k2, qF[kd], s1);
            }
        }
        PRIO(0);

        // fixed-scale softmax: p = 2^s via native v_exp; diagonal masked
        float ps = 0.f;
        u32 pkA[8], pkB[8];
        if (d0) {
#pragma unroll
            for (int r2 = 0; r2 < 16; r2++) {
                int ka = (r2 & 3) + 4 * ((r2 >> 2) & 1) + 16 * (r2 >> 3) + 8 * H;
                if (ka > lq) s0[r2] = -1e30f;
            }
        }
#pragma unroll
        for (int i = 0; i < 8; i++) {
            float a = fexp2(s0[2 * i]), b2 = fexp2(s0[2 * i + 1]);
            ps += a + b2; pkA[i] = cvt_pk_bf16(a, b2);
        }
        if (c1) {
            if (d1) {
#pragma unroll
                for (int r2 = 0; r2 < 16; r2++) {
                    int ka = (r2 & 3) + 4 * ((r2 >> 2) & 1) + 16 * (r2 >> 3) + 8 * H;
                    if (ka > lq) s1[r2] = -1e30f;
                }
            }
#pragma unroll
            for (int i = 0; i < 8; i++) {
                float a = fexp2(s1[2 * i]), b2 = fexp2(s1[2 * i + 1]);
                ps += a + b2; pkB[i] = cvt_pk_bf16(a, b2);
            }
        }
        lsum += ps;                                   // cross-half reduce deferred

        // PV: A-frags direct from pk words (zero shuffle); B = contiguous V runs
        PRIO(1);
        {
            u32x4 a0 = {pkA[0], pkA[1], pkA[2], pkA[3]};
            u32x4 a1 = {pkA[4], pkA[5], pkA[6], pkA[7]};
            bfrag A0 = __builtin_bit_cast(bfrag, a0);
            bfrag A1 = __builtin_bit_cast(bfrag, a1);
            bfrag v00 = *(const bfrag*)(vl + lq * 64 + ((H) ^ vsw) * 8);
            bfrag v01 = *(const bfrag*)(vl + (32 + lq) * 64 + ((H) ^ vsw) * 8);
            bfrag v10 = *(const bfrag*)(vl + lq * 64 + ((2 + H) ^ vsw) * 8);
            bfrag v11 = *(const bfrag*)(vl + (32 + lq) * 64 + ((2 + H) ^ vsw) * 8);
            O0 = mfma32(A0, v00, O0);
            O1 = mfma32(A0, v01, O1);
            O0 = mfma32(A1, v10, O0);
            O1 = mfma32(A1, v11, O1);
        }
        if (c1) {
            u32x4 a0 = {pkB[0], pkB[1], pkB[2], pkB[3]};
            u32x4 a1 = {pkB[4], pkB[5], pkB[6], pkB[7]};
            bfrag A0 = __builtin_bit_cast(bfrag, a0);
            bfrag A1 = __builtin_bit_cast(bfrag, a1);
            bfrag v00 = *(const bfrag*)(vl + lq * 64 + ((4 + H) ^ vsw) * 8);
            bfrag v01 = *(const bfrag*)(vl + (32 + lq) * 64 + ((4 + H) ^ vsw) * 8);
            bfrag v10 = *(const bfrag*)(vl + lq * 64 + ((6 + H) ^ vsw) * 8);
            bfrag v11 = *(const bfrag*)(vl + (32 + lq) * 64 + ((6 + H) ^ vsw) * 8);
            O0 = mfma32(A0, v00, O0);
            O1 = mfma32(A0, v01, O1);
            O0 = mfma32(A1, v10, O0);
            O1 = mfma32(A1, v11, O1);
        }
        PRIO(0);
        win = winn; pb = pbn;
        cur = nxt;
        nxt = (nxt == 2) ? 0 : nxt + 1;
    }

    float lsT = lsum + __shfl_xor(lsum, 32);
    if (np == 1) {
        // single piece == full tile: normalize and write o directly
        float linv = 1.f / lsT;
        const int b = bh / 12, h = bh % 12;
#pragma unroll
        for (int r2 = 0; r2 < 16; r2++) {
            int row = (r2 & 3) + 8 * (r2 >> 2) + 4 * H;
            float fr = __shfl(linv, row);
            size_t base = ((size_t)(b * 2048 + qw0 + row)) * 768 + h * 64;
            o_ws[base + lq] = f2bf(O0[r2] * fr);
            o_ws[base + 32 + lq] = f2bf(O1[r2] * fr);
        }
    } else {
        // partial store: po[q][d] bf16 + l (combine normalizes)
        const int cum8[8] = {0, 8, 16, 32, 48, 72, 96, 128};
        size_t pidx = (size_t)bh * 160 + cum8[t7] + ti * np + piece;
        u16* po = po_ws + pidx * 2048;
#pragma unroll
        for (int r2 = 0; r2 < 16; r2++) {
            int row = (r2 & 3) + 8 * (r2 >> 2) + 4 * H;   // query row (unpermuted)
            po[row * 64 + lq] = f2bf(O0[r2]);
            po[row * 64 + 32 + lq] = f2bf(O1[r2]);
        }
        if (l < 32) l_ws[pidx * 32 + lq] = lsT;
    }
}

// ---------------- combine partial O pieces (t7 >= 2 tiles only) ----------------
__global__ __launch_bounds__(256) void combine_o(
    const u16* __restrict__ po_ws, const float* __restrict__ l_ws,
    u16* __restrict__ o_ws) {
    int id = blockIdx.x;                              // 1152 = 24 bh x 48 tiles (t7>=2)
    int bh8 = id & 7, idq = id >> 3;
    int bhq = idq % 3, r = idq / 3;
    int bh = bhq * 8 + bh8;
    int t7 = 2 + (r >> 3), ti = r & 7;
    int tile = t7 + 8 * ti;
    int np = (t7 + 2) >> 1;
    const int cum8[8] = {0, 8, 16, 32, 48, 72, 96, 128};
    size_t base = (size_t)bh * 160 + cum8[t7] + ti * np;
    int t = threadIdx.x;
    int q = t >> 3, d8 = (t & 7) * 8;
    float acc[8] = {0.f, 0.f, 0.f, 0.f, 0.f, 0.f, 0.f, 0.f};
    float lt = 0.f;
    for (int i = 0; i < np; i++) {
        lt += l_ws[(base + i) * 32 + q];
        bfrag v = *(const bfrag*)(po_ws + (base + i) * 2048 + q * 64 + d8);
#pragma unroll
        for (int e = 0; e < 8; e++)
            acc[e] += __uint_as_float(((u32)(u16)v[e]) << 16);
    }
    float inv = 1.f / lt;
    u32x4 pkv;
#pragma unroll
    for (int e = 0; e < 4; e++)
        pkv[e] = cvt_pk_bf16(acc[2 * e] * inv, acc[2 * e + 1] * inv);
    int b = bh / 12, h = bh % 12;
    size_t dst = ((size_t)(b * 2048 + tile * 32 + q)) * 768 + h * 64 + d8;
    *(u32x4*)(o_ws + dst) = pkv;
}

// ---------------- launcher ----------------
extern "C" void kernel_launch(void* const* d_in, const int* in_sizes, int n_in,
                              void* d_out, int out_size, void* d_ws, size_t ws_size,
                              hipStream_t stream) {
    const float* x  = (const float*)d_in[0];
    const float* Wq = (const float*)d_in[1];
    const float* bq = (const float*)d_in[2];
    const float* Wk = (const float*)d_in[3];
    const float* bk = (const float*)d_in[4];
    const float* Wv = (const float*)d_in[5];
    const float* bv = (const float*)d_in[6];
    const float* Wo = (const float*)d_in[7];
    const float* bo = (const float*)d_in[8];
    float* out = (float*)d_out;

    char* p = (char*)d_ws;
    u16*   q_ws  = (u16*)(p + 0);
    u16*   k_ws  = (u16*)(p + 6291456);
    u16*   vt_ws = (u16*)(p + 12582912);
    u16*   po_ws = (u16*)(p + 18874368);
    u16*   xb    = (u16*)(p + 18874368);              // overlay
    u16*   wqb   = (u16*)(p + 25165824);
    u16*   wkb   = (u16*)(p + 26345472);
    u16*   wvb   = (u16*)(p + 27525120);
    float* l_ws  = (float*)(p + 34603008);
    u16*   wob   = (u16*)(p + 35094528);
    u16*   o_ws  = (u16*)(p + 36274176);

    convert_all<<<5376, 256, 0, stream>>>(x, Wq, Wk, Wv, Wo, xb, wqb, wkb, wvb, wob);
    gemm_qkv<<<dim3(32, 18), 256, 0, stream>>>(xb, wqb, wkb, wvb, bq, bk, bv, q_ws, k_ws, vt_ws);
    attn13<<<dim3(480), 512, 0, stream>>>(q_ws, k_ws, vt_ws, o_ws, po_ws, l_ws);
    combine_o<<<dim3(1152), 256, 0, stream>>>(po_ws, l_ws, o_ws);
    gemm_out64<<<dim3(64, 6), 256, 0, stream>>>(o_ws, wob, bo, out);
}